// Round 3
// baseline (2691.821 us; speedup 1.0000x reference)
//
#include <hip/hip_runtime.h>

typedef unsigned short u16;
typedef short bf8 __attribute__((ext_vector_type(8)));
typedef float f4 __attribute__((ext_vector_type(4)));

#define N_NODES 20000
#define N_EDGES 320000
#define NGRAPH 40
#define NPG 500
#define KTOP 250

// parms arena offsets (u16 elements, all 16B-aligned)
#define P_CONV_BIAS 0
#define P_POOL_W    768
#define P_POOL_ROOT 6912
#define P_POOL_BIAS 7680
#define P_FC1_W     7688
#define P_FC1_B     204296
#define P_W_IH      204552
#define P_B_IH      466696
#define P_B_HH      467720
#define P_FC2_W     468744
#define P_FC2_B     469256
#define P_TOTAL     469264

__device__ __forceinline__ float b2f(u16 u) {
    union { unsigned int i; float f; } v; v.i = ((unsigned int)u) << 16; return v.f;
}
__device__ __forceinline__ u16 f2b(float f) {
    union { float f; unsigned int i; } v; v.f = f;
    unsigned int x = v.i;
    return (u16)((x + 0x7fffu + ((x >> 16) & 1u)) >> 16);
}
__device__ __forceinline__ float wred(float s) {
    #pragma unroll
    for (int off = 32; off > 0; off >>= 1) s += __shfl_down(s, off);
    return s;
}

// ---------------- dtype detection ----------------
// If the float inputs are fp32 misread as bf16, ~1/256 of low-half u16s decode
// as bf16 NaN/Inf (exp bits all 1). Genuine bf16 normals: zero such patterns.
__global__ void k_detect(const u16* __restrict__ xr, int n, unsigned int* __restrict__ flag) {
    __shared__ unsigned int cnt_s;
    if (threadIdx.x == 0) cnt_s = 0u;
    __syncthreads();
    unsigned int local = 0;
    for (int i = threadIdx.x; i < n; i += 1024) {
        unsigned int u = xr[i];
        if (((u >> 7) & 0xFFu) == 0xFFu) local++;
    }
    if (local) atomicAdd(&cnt_s, local);
    __syncthreads();
    if (threadIdx.x == 0) *flag = (cnt_s > 8u) ? 1u : 0u;
}

__device__ __forceinline__ u16 load_cvt(const void* src, size_t i, bool f32) {
    return f32 ? f2b(((const float*)src)[i]) : ((const u16*)src)[i];
}

__global__ void k_convert(const void* __restrict__ src, u16* __restrict__ dst, int n,
                          const unsigned int* __restrict__ flag) {
    int i = blockIdx.x * 256 + threadIdx.x;
    if (i >= n) return;
    dst[i] = load_cvt(src, i, *flag != 0u);
}

// stage x (canonical bf16) into xc[:, 512:768]; layer 2 overwrites this region
// only after layer 0 has consumed it.
__global__ void k_stage_x(const void* __restrict__ src, u16* __restrict__ xc,
                          const unsigned int* __restrict__ flag) {
    int i = blockIdx.x * 256 + threadIdx.x;
    if (i >= N_NODES * 256) return;
    u16 v = load_cvt(src, i, *flag != 0u);
    int n = i >> 8, f = i & 255;
    xc[(size_t)n * 768 + 512 + f] = v;
}

// ---------------- setup kernels ----------------
__global__ void k_zero_u32(unsigned int* p, int n) {
    int i = blockIdx.x * 256 + threadIdx.x;
    if (i < n) p[i] = 0u;
}
__global__ void k_count(const int* __restrict__ dst, const int* __restrict__ et,
                        unsigned int* __restrict__ cnt) {
    int e = blockIdx.x * 256 + threadIdx.x;
    if (e < N_EDGES) {
        unsigned d = (unsigned)dst[e]; if (d >= N_NODES) d = 0;
        unsigned r = (unsigned)et[e] & 7u;
        atomicAdd(&cnt[d * 8 + r], 1u);
    }
}
__global__ void k_inv(const unsigned int* __restrict__ cnt, float* __restrict__ inv, int n) {
    int i = blockIdx.x * 256 + threadIdx.x;
    if (i < n) {
        unsigned int c = cnt[i];
        inv[i] = 1.0f / (float)(c < 1u ? 1u : c);
    }
}
// conv_W [l][r][i][o], conv_root [l][i][o]  ->  Wt [l][rr][o][i]  (rr=8 is root)
__global__ void k_transpose(const void* __restrict__ conv_W, const void* __restrict__ conv_root,
                            u16* __restrict__ Wt, const unsigned int* __restrict__ flag) {
    int idx = blockIdx.x * 256 + threadIdx.x;      // ((l*9+rr)*256 + o)*256 + i
    if (idx >= 3 * 9 * 256 * 256) return;
    bool f32 = (*flag != 0u);
    int i = idx & 255;
    int o = (idx >> 8) & 255;
    int lr = idx >> 16;
    int l = lr / 9, rr = lr % 9;
    u16 v;
    if (rr < 8) v = load_cvt(conv_W, (size_t)(((l * 8 + rr) * 256 + i) << 8) + o, f32);
    else        v = load_cvt(conv_root, (size_t)(((l * 256 + i) << 8) + o), f32);
    Wt[idx] = v;
}
// W_hh [j][i] -> whh_t[(i>>3)][j][(i&7)]
__global__ void k_thh(const void* __restrict__ W_hh, u16* __restrict__ whh_t,
                      const unsigned int* __restrict__ flag) {
    int idx = blockIdx.x * 256 + threadIdx.x;      // 262144
    if (idx >= 1024 * 256) return;
    int j = idx >> 8, i = idx & 255;
    whh_t[((i >> 3) << 13) + (j << 3) + (i & 7)] = load_cvt(W_hh, idx, *flag != 0u);
}

// ---------------- RGCN GEMM over an FT-wide output-column tile ----------------
// A: [20000, 768] bf16 rows (xc-resident).  WtL: 9 matrices [256(out),256(in)] bf16.
// rr<8 -> bf16 into T [N,FT]; rr==8 -> fp32 agg[N,FT] = val + bias (root term).
template<int FT>
__launch_bounds__(256)
__global__ void k_gemm(const u16* __restrict__ A, const u16* __restrict__ WtL,
                       u16* __restrict__ T, float* __restrict__ agg,
                       const u16* __restrict__ bias, int rr, int f0) {
    constexpr int NT = FT / 16;
    const u16* Bt = WtL + rr * 65536;
    int wave = threadIdx.x >> 6;
    int lane = threadIdx.x & 63;
    int m0 = (blockIdx.x * 4 + wave) * 16;
    if (m0 >= N_NODES) return;
    int mrow = lane & 15, quad = lane >> 4;
    const u16* abase = A + (size_t)(m0 + mrow) * 768 + quad * 8;
    const u16* bbase = Bt + (size_t)(f0 + mrow) * 256 + quad * 8;

    f4 acc[NT];
    #pragma unroll
    for (int t = 0; t < NT; ++t) acc[t] = (f4){0.0f, 0.0f, 0.0f, 0.0f};

    #pragma unroll
    for (int kt = 0; kt < 8; ++kt) {
        bf8 a = *(const bf8*)(abase + kt * 32);
        #pragma unroll
        for (int nt = 0; nt < NT; ++nt) {
            bf8 b = *(const bf8*)(bbase + nt * 4096 + kt * 32);
            acc[nt] = __builtin_amdgcn_mfma_f32_16x16x32_bf16(a, b, acc[nt], 0, 0, 0);
        }
    }

    int rq = quad * 4;
    if (rr < 8) {
        #pragma unroll
        for (int nt = 0; nt < NT; ++nt)
            #pragma unroll
            for (int v = 0; v < 4; ++v)
                T[(size_t)(m0 + rq + v) * FT + nt * 16 + mrow] = f2b(acc[nt][v]);
    } else {
        #pragma unroll
        for (int nt = 0; nt < NT; ++nt)
            #pragma unroll
            for (int v = 0; v < 4; ++v) {
                int of = nt * 16 + mrow;
                agg[(size_t)(m0 + rq + v) * FT + of] = acc[nt][v] + b2f(bias[f0 + of]);
            }
    }
}

// ---------------- edge scatter: agg[dst] += inv * T[src] for edges of relation r ----------------
template<int FT>
__global__ void k_scatter(const int* __restrict__ src, const int* __restrict__ dst,
                          const int* __restrict__ et, const float* __restrict__ inv,
                          const u16* __restrict__ T, float* __restrict__ agg, int r_filter) {
    int e = blockIdx.x * 4 + (threadIdx.x >> 6);
    if (e >= N_EDGES) return;
    int r = et[e] & 7;
    if (r != r_filter) return;
    int lane = threadIdx.x & 63;
    unsigned s = (unsigned)src[e]; if (s >= N_NODES) s = 0;
    unsigned d = (unsigned)dst[e]; if (d >= N_NODES) d = 0;
    float w = inv[d * 8 + r];
    #pragma unroll
    for (int q0 = 0; q0 < FT / 64; ++q0) {
        int q = lane + q0 * 64;
        atomicAdd(&agg[(size_t)d * FT + q], w * b2f(T[(size_t)s * FT + q]));
    }
}

template<int FT>
__global__ void k_finalize(const float* __restrict__ agg, u16* __restrict__ xc, int colbase) {
    int i = blockIdx.x * 256 + threadIdx.x;
    if (i >= N_NODES * FT) return;
    int n = i / FT, of = i % FT;
    float v = agg[i];
    v = v > 0.0f ? v : 0.0f;
    xc[(size_t)n * 768 + colbase + of] = f2b(v);
}

// ---------------- pool scorer ----------------
__global__ void k_pool(const u16* __restrict__ xc, const u16* __restrict__ parms,
                       float* __restrict__ p, float* __restrict__ score) {
    int wid = blockIdx.x * 4 + (threadIdx.x >> 6);
    if (wid >= N_NODES * 9) return;
    int n = wid / 9, rr = wid % 9;
    int lane = threadIdx.x & 63;
    const u16* xr = xc + (size_t)n * 768;
    const u16* w = (rr < 8) ? (parms + P_POOL_W + rr * 768) : (parms + P_POOL_ROOT);
    float s = 0.0f;
    #pragma unroll
    for (int q = 0; q < 12; ++q) { int f = lane + 64 * q; s += b2f(xr[f]) * b2f(w[f]); }
    s = wred(s);
    if (lane == 0) {
        if (rr < 8) p[rr * N_NODES + n] = s;
        else        score[n] = s + b2f(parms[P_POOL_BIAS]);
    }
}
__global__ void k_scatter_pool(const int* __restrict__ src, const int* __restrict__ dst,
                               const int* __restrict__ et, const float* __restrict__ inv,
                               const float* __restrict__ p, float* __restrict__ score) {
    int e = blockIdx.x * 256 + threadIdx.x;
    if (e >= N_EDGES) return;
    int r = et[e] & 7;
    unsigned s = (unsigned)src[e]; if (s >= N_NODES) s = 0;
    unsigned d = (unsigned)dst[e]; if (d >= N_NODES) d = 0;
    atomicAdd(&score[d], inv[d * 8 + r] * p[r * N_NODES + s]);
}

// ---------------- per-graph top-K + weighted-mean readout ----------------
__launch_bounds__(256)
__global__ void k_topk(const float* __restrict__ score, const u16* __restrict__ xc,
                       float* __restrict__ readout) {
    __shared__ unsigned long long keys[512];
    __shared__ float vals[512];
    int g = blockIdx.x, tid = threadIdx.x;
    for (int i = tid; i < 512; i += 256) {
        unsigned long long key;
        float v = 0.0f;
        if (i < NPG) {
            v = tanhf(score[g * NPG + i]);
            unsigned int u = __float_as_uint(v);
            u = (u & 0x80000000u) ? ~u : (u | 0x80000000u);  // monotone map
            u = ~u;                                          // descending score
            key = ((unsigned long long)u << 32) | (unsigned int)i;
        } else {
            key = 0xFFFFFFFFFFFFFFFFull;
        }
        keys[i] = key;
        vals[i] = v;
    }
    __syncthreads();
    for (int k = 2; k <= 512; k <<= 1)
        for (int j = k >> 1; j > 0; j >>= 1) {
            for (int i = tid; i < 512; i += 256) {
                int ixj = i ^ j;
                if (ixj > i) {
                    bool up = ((i & k) == 0);
                    unsigned long long a = keys[i], b = keys[ixj];
                    if ((a > b) == up) { keys[i] = b; keys[ixj] = a; }
                }
            }
            __syncthreads();
        }
    float a0 = 0.0f, a1 = 0.0f, a2 = 0.0f;
    for (int jj = 0; jj < KTOP; ++jj) {
        int idx = (int)(keys[jj] & 511u);
        if (idx >= NPG) continue;                            // safety: never OOB
        float v = vals[idx];
        const u16* xr = xc + (size_t)(g * NPG + idx) * 768;
        a0 += v * b2f(xr[tid]);
        a1 += v * b2f(xr[tid + 256]);
        a2 += v * b2f(xr[tid + 512]);
    }
    const float sc = 1.0f / (float)KTOP;
    readout[(size_t)g * 768 + tid]       = a0 * sc;
    readout[(size_t)g * 768 + tid + 256] = a1 * sc;
    readout[(size_t)g * 768 + tid + 512] = a2 * sc;
}

// ---------------- fc1 + LSTM input precompute ----------------
__global__ void k_fc1(const float* __restrict__ readout, const u16* __restrict__ parms,
                      float* __restrict__ h1) {
    int wid = blockIdx.x * 4 + (threadIdx.x >> 6);
    if (wid >= NGRAPH * 256) return;
    int g = wid >> 8, o = wid & 255, lane = threadIdx.x & 63;
    const float* rr = readout + (size_t)g * 768;
    const u16* w = parms + P_FC1_W + (size_t)o * 768;
    float s = 0.0f;
    #pragma unroll
    for (int q = 0; q < 12; ++q) { int f = lane + 64 * q; s += rr[f] * b2f(w[f]); }
    s = wred(s);
    if (lane == 0) { s += b2f(parms[P_FC1_B + o]); h1[g * 256 + o] = s > 0.0f ? s : 0.0f; }
}
__global__ void k_gx(const float* __restrict__ h1, const u16* __restrict__ parms,
                     float* __restrict__ gx) {
    int wid = blockIdx.x * 4 + (threadIdx.x >> 6);
    if (wid >= NGRAPH * 1024) return;
    int t = wid >> 10, j = wid & 1023, lane = threadIdx.x & 63;
    const float* xr = h1 + t * 256;
    const u16* w = parms + P_W_IH + (size_t)j * 256;
    float s = 0.0f;
    #pragma unroll
    for (int q = 0; q < 4; ++q) { int f = lane + 64 * q; s += xr[f] * b2f(w[f]); }
    s = wred(s);
    if (lane == 0) gx[t * 1024 + j] = s + b2f(parms[P_B_IH + j]) + b2f(parms[P_B_HH + j]);
}

// ---------------- sequential LSTM (single block) + fc2 + log_softmax ----------------
__launch_bounds__(1024)
__global__ void k_lstm(const float* __restrict__ gx, const u16* __restrict__ whh_t,
                       const u16* __restrict__ parms, void* __restrict__ out,
                       const unsigned int* __restrict__ flag) {
    __shared__ float hs[256];
    __shared__ float gs[1024];
    __shared__ float red[2];
    int tid = threadIdx.x;
    if (tid < 256) hs[tid] = 0.0f;
    float c = 0.0f;
    __syncthreads();
    for (int t = 0; t < NGRAPH; ++t) {
        float g = gx[t * 1024 + tid];
        #pragma unroll 4
        for (int ib = 0; ib < 32; ++ib) {
            bf8 wv = *(const bf8*)(whh_t + (ib << 13) + (tid << 3));
            #pragma unroll
            for (int q = 0; q < 8; ++q) g += b2f((u16)wv[q]) * hs[ib * 8 + q];
        }
        gs[tid] = g;
        __syncthreads();
        if (tid < 256) {
            float gi = 1.0f / (1.0f + expf(-gs[tid]));
            float gf = 1.0f / (1.0f + expf(-gs[256 + tid]));
            float gg = tanhf(gs[512 + tid]);
            float go = 1.0f / (1.0f + expf(-gs[768 + tid]));
            c = gf * c + gi * gg;
            hs[tid] = go * tanhf(c);
        }
        __syncthreads();
    }
    if (tid < 128) {
        int cls = tid >> 6, lane = tid & 63;
        float s = 0.0f;
        #pragma unroll
        for (int q = 0; q < 4; ++q) {
            int d = lane + 64 * q;
            s += hs[d] * b2f(parms[P_FC2_W + cls * 256 + d]);
        }
        s = wred(s);
        if (lane == 0) red[cls] = s + b2f(parms[P_FC2_B + cls]);
    }
    __syncthreads();
    if (tid == 0) {
        float l0 = red[0], l1 = red[1];
        float m = fmaxf(l0, l1);
        float lse = m + logf(expf(l0 - m) + expf(l1 - m));
        float o0 = l0 - lse, o1 = l1 - lse;
        if (*flag) { ((float*)out)[0] = o0; ((float*)out)[1] = o1; }
        else       { ((u16*)out)[0] = f2b(o0); ((u16*)out)[1] = f2b(o1); }
    }
}

// ---------------- workspace plan ----------------
struct WS {
    unsigned int* flag; unsigned int* cnt; float* inv; u16* Wt; u16* t; float* agg;
    u16* xc; float* p; float* score; float* readout; float* h1; float* gx;
    u16* whh_t; u16* parms;
    size_t need;
};
static WS plan(char* base, int FT) {
    WS w; size_t off = 0;
    auto take = [&](size_t bytes) -> char* {
        char* p = base + off; off += (bytes + 255) & ~(size_t)255; return p;
    };
    w.flag    = (unsigned int*)take(256);
    w.cnt     = (unsigned int*)take(160000 * 4);
    w.inv     = (float*)take(160000 * 4);
    w.Wt      = (u16*)take((size_t)27 * 65536 * 2);
    w.t       = (u16*)take((size_t)N_NODES * FT * 2);
    w.agg     = (float*)take((size_t)N_NODES * FT * 4);
    w.xc      = (u16*)take((size_t)N_NODES * 768 * 2);
    w.p       = (float*)take((size_t)8 * N_NODES * 4);
    w.score   = (float*)take((size_t)N_NODES * 4);
    w.readout = (float*)take((size_t)NGRAPH * 768 * 4);
    w.h1      = (float*)take((size_t)NGRAPH * 256 * 4);
    w.gx      = (float*)take((size_t)NGRAPH * 1024 * 4);
    w.whh_t   = (u16*)take((size_t)1024 * 256 * 2);
    w.parms   = (u16*)take((size_t)P_TOTAL * 2);
    w.need = off;
    return w;
}

template<int FT>
static void run_layers(const WS& w, const int* e_src, const int* e_dst,
                       const int* edge_attr, hipStream_t stream) {
    const int gemm_gx = (N_NODES / 16 + 3) / 4;   // 313
    const int fin_gx = (N_NODES * FT + 255) / 256;
    for (int l = 0; l < 3; ++l) {
        // layer 0 input: canonical-bf16 x staged at xc cols [512,768)
        const u16* A = w.xc + (l == 0 ? 512 : (l - 1) * 256);
        const u16* WtL = w.Wt + (size_t)l * 9 * 65536;
        const u16* bias = w.parms + P_CONV_BIAS + l * 256;
        for (int f0 = 0; f0 < 256; f0 += FT) {
            k_gemm<FT><<<gemm_gx, 256, 0, stream>>>(A, WtL, w.t, w.agg, bias, 8, f0);
            for (int r = 0; r < 8; ++r) {
                k_gemm<FT><<<gemm_gx, 256, 0, stream>>>(A, WtL, w.t, w.agg, bias, r, f0);
                k_scatter<FT><<<80000, 256, 0, stream>>>(e_src, e_dst, edge_attr, w.inv,
                                                         w.t, w.agg, r);
            }
            k_finalize<FT><<<fin_gx, 256, 0, stream>>>(w.agg, w.xc, l * 256 + f0);
        }
    }
}

extern "C" void kernel_launch(void* const* d_in, const int* in_sizes, int n_in,
                              void* d_out, int out_size, void* d_ws, size_t ws_size,
                              hipStream_t stream) {
    (void)in_sizes; (void)n_in; (void)out_size;
    const void* x        = d_in[0];
    const int* edge_index= (const int*)d_in[1];
    const int* edge_attr = (const int*)d_in[2];
    const void* conv_W   = d_in[4];
    const void* conv_root= d_in[5];
    const void* conv_bias= d_in[6];
    const void* pool_W   = d_in[7];
    const void* pool_root= d_in[8];
    const void* pool_bias= d_in[9];
    const void* fc1_W    = d_in[10];
    const void* fc1_b    = d_in[11];
    const void* W_ih     = d_in[12];
    const void* W_hh     = d_in[13];
    const void* b_ih     = d_in[14];
    const void* b_hh     = d_in[15];
    const void* fc2_W    = d_in[16];
    const void* fc2_b    = d_in[17];

    const int* e_src = edge_index;
    const int* e_dst = edge_index + N_EDGES;

    // pick the widest feature tile that fits ws_size (host-side, deterministic)
    int FT = 64;
    if (plan((char*)d_ws, 256).need <= ws_size)      FT = 256;
    else if (plan((char*)d_ws, 128).need <= ws_size) FT = 128;
    WS w = plan((char*)d_ws, FT);

    // dtype detect (bf16 vs fp32 inputs), then canonicalize everything to bf16
    k_detect<<<1, 1024, 0, stream>>>((const u16*)x, 1 << 20, w.flag);

    k_zero_u32<<<625, 256, 0, stream>>>(w.cnt, 160000);
    k_count<<<1250, 256, 0, stream>>>(e_dst, edge_attr, w.cnt);
    k_inv<<<625, 256, 0, stream>>>(w.cnt, w.inv, 160000);

    auto cvt = [&](const void* src, int parm_off, int n) {
        k_convert<<<(n + 255) / 256, 256, 0, stream>>>(src, w.parms + parm_off, n, w.flag);
    };
    cvt(conv_bias, P_CONV_BIAS, 768);
    cvt(pool_W,    P_POOL_W,    6144);
    cvt(pool_root, P_POOL_ROOT, 768);
    cvt(pool_bias, P_POOL_BIAS, 1);
    cvt(fc1_W,     P_FC1_W,     196608);
    cvt(fc1_b,     P_FC1_B,     256);
    cvt(W_ih,      P_W_IH,      262144);
    cvt(b_ih,      P_B_IH,      1024);
    cvt(b_hh,      P_B_HH,      1024);
    cvt(fc2_W,     P_FC2_W,     512);
    cvt(fc2_b,     P_FC2_B,     2);

    k_stage_x<<<20000, 256, 0, stream>>>(x, w.xc, w.flag);
    k_transpose<<<6912, 256, 0, stream>>>(conv_W, conv_root, w.Wt, w.flag);
    k_thh<<<1024, 256, 0, stream>>>(W_hh, w.whh_t, w.flag);

    if (FT == 256)      run_layers<256>(w, e_src, e_dst, edge_attr, stream);
    else if (FT == 128) run_layers<128>(w, e_src, e_dst, edge_attr, stream);
    else                run_layers<64> (w, e_src, e_dst, edge_attr, stream);

    k_pool<<<45000, 256, 0, stream>>>(w.xc, w.parms, w.p, w.score);
    k_scatter_pool<<<1250, 256, 0, stream>>>(e_src, e_dst, edge_attr, w.inv, w.p, w.score);
    k_topk<<<NGRAPH, 256, 0, stream>>>(w.score, w.xc, w.readout);
    k_fc1<<<2560, 256, 0, stream>>>(w.readout, w.parms, w.h1);
    k_gx<<<10240, 256, 0, stream>>>(w.h1, w.parms, w.gx);
    k_lstm<<<1, 1024, 0, stream>>>(w.gx, w.whh_t, w.parms, d_out, w.flag);
}

// Round 4
// 1250.124 us; speedup vs baseline: 2.1532x; 2.1532x over previous
//
#include <hip/hip_runtime.h>

typedef unsigned short u16;
typedef short bf8 __attribute__((ext_vector_type(8)));
typedef float f4 __attribute__((ext_vector_type(4)));

#define N_NODES 20000
#define N_EDGES 320000
#define NGRAPH 40
#define NPG 500
#define KTOP 250
#define NSEG (N_NODES * 8)
#define NM (N_NODES * 256)

// parms arena offsets (u16 elements, all 16B-aligned)
#define P_CONV_BIAS 0
#define P_POOL_W    768
#define P_POOL_ROOT 6912
#define P_POOL_BIAS 7680
#define P_FC1_W     7688
#define P_FC1_B     204296
#define P_W_IH      204552
#define P_B_IH      466696
#define P_B_HH      467720
#define P_FC2_W     468744
#define P_FC2_B     469256
#define P_TOTAL     469264

__device__ __forceinline__ float b2f(u16 u) {
    union { unsigned int i; float f; } v; v.i = ((unsigned int)u) << 16; return v.f;
}
__device__ __forceinline__ u16 f2b(float f) {
    union { float f; unsigned int i; } v; v.f = f;
    unsigned int x = v.i;
    return (u16)((x + 0x7fffu + ((x >> 16) & 1u)) >> 16);
}
__device__ __forceinline__ float wred(float s) {
    #pragma unroll
    for (int off = 32; off > 0; off >>= 1) s += __shfl_down(s, off);
    return s;
}

// ---------------- dtype detection (parallel) ----------------
__global__ void k_detect1(const u16* __restrict__ xr, int n, unsigned int* __restrict__ fb) {
    unsigned int local = 0;
    for (int i = blockIdx.x * 256 + threadIdx.x; i < n; i += 64 * 256) {
        unsigned int u = xr[i];
        if (((u >> 7) & 0xFFu) == 0xFFu) local++;
    }
    local = (unsigned int)wred((float)local);      // wave sum (exact: small ints)
    if ((threadIdx.x & 63) == 0 && local) atomicAdd(&fb[1], local);
}
__global__ void k_detect2(unsigned int* __restrict__ fb) {
    fb[0] = (fb[1] > 8u) ? 1u : 0u;
}

__device__ __forceinline__ u16 load_cvt(const void* src, size_t i, bool f32) {
    return f32 ? f2b(((const float*)src)[i]) : ((const u16*)src)[i];
}

__global__ void k_convert(const void* __restrict__ src, u16* __restrict__ dst, int n,
                          const unsigned int* __restrict__ flag) {
    int i = blockIdx.x * 256 + threadIdx.x;
    if (i >= n) return;
    dst[i] = load_cvt(src, i, *flag != 0u);
}

// stage x (canonical bf16) into xc[:, 512:768]; layer 2 overwrites this region
// only after layer 0 has consumed it.
__global__ void k_stage_x(const void* __restrict__ src, u16* __restrict__ xc,
                          const unsigned int* __restrict__ flag) {
    int i = blockIdx.x * 256 + threadIdx.x;
    if (i >= N_NODES * 256) return;
    u16 v = load_cvt(src, i, *flag != 0u);
    int n = i >> 8, f = i & 255;
    xc[(size_t)n * 768 + 512 + f] = v;
}

// ---------------- setup kernels ----------------
__global__ void k_zero_u32(unsigned int* p, int n) {
    int i = blockIdx.x * 256 + threadIdx.x;
    if (i < n) p[i] = 0u;
}
__global__ void k_count(const int* __restrict__ dst, const int* __restrict__ et,
                        unsigned int* __restrict__ cnt) {
    int e = blockIdx.x * 256 + threadIdx.x;
    if (e < N_EDGES) {
        unsigned d = (unsigned)dst[e]; if (d >= N_NODES) d = 0;
        unsigned r = (unsigned)et[e] & 7u;
        atomicAdd(&cnt[d * 8 + r], 1u);
    }
}
__global__ void k_inv(const unsigned int* __restrict__ cnt, float* __restrict__ inv, int n) {
    int i = blockIdx.x * 256 + threadIdx.x;
    if (i < n) {
        unsigned int c = cnt[i];
        inv[i] = 1.0f / (float)(c < 1u ? 1u : c);
    }
}

// ---------------- prefix scan (exclusive) over cnt[160000] ----------------
__global__ void k_scan1(const unsigned int* __restrict__ cnt, unsigned int* __restrict__ seg,
                        unsigned int* __restrict__ bsum) {
    __shared__ unsigned int s[256];
    int t = threadIdx.x, i = blockIdx.x * 256 + t;
    unsigned int v = (i < NSEG) ? cnt[i] : 0u;
    s[t] = v;
    __syncthreads();
    for (int off = 1; off < 256; off <<= 1) {
        unsigned int add = (t >= off) ? s[t - off] : 0u;
        __syncthreads();
        s[t] += add;
        __syncthreads();
    }
    if (i < NSEG) seg[i] = s[t] - v;
    if (t == 255) bsum[blockIdx.x] = s[255];
}
__global__ void k_scan2(unsigned int* __restrict__ bsum, int nb) {
    __shared__ unsigned int s[1024];
    int t = threadIdx.x;
    unsigned int v = (t < nb) ? bsum[t] : 0u;
    s[t] = v;
    __syncthreads();
    for (int off = 1; off < 1024; off <<= 1) {
        unsigned int add = (t >= off) ? s[t - off] : 0u;
        __syncthreads();
        s[t] += add;
        __syncthreads();
    }
    if (t < nb) bsum[t] = s[t] - v;
}
__global__ void k_scan3(unsigned int* __restrict__ seg, const unsigned int* __restrict__ bsum) {
    int i = blockIdx.x * 256 + threadIdx.x;
    if (i < NSEG) seg[i] += bsum[i >> 8];
    if (i == 0) seg[NSEG] = N_EDGES;
}
// place edges into (dst,rel)-sorted order
__global__ void k_place(const int* __restrict__ src, const int* __restrict__ dst,
                        const int* __restrict__ et, const unsigned int* __restrict__ seg,
                        unsigned int* __restrict__ ctr, const float* __restrict__ inv,
                        unsigned int* __restrict__ skey, float* __restrict__ sw) {
    int e = blockIdx.x * 256 + threadIdx.x;
    if (e >= N_EDGES) return;
    unsigned s = (unsigned)src[e]; if (s >= N_NODES) s = 0;
    unsigned d = (unsigned)dst[e]; if (d >= N_NODES) d = 0;
    unsigned r = (unsigned)et[e] & 7u;
    unsigned key = d * 8 + r;
    unsigned pos = seg[key] + atomicAdd(&ctr[key], 1u);
    skey[pos] = r * N_NODES + s;
    sw[pos] = inv[key];
}

// ---------------- RGCN GEMM ----------------
// A: [20000,768] bf16 rows (xc-resident).  WtL: 9 matrices [256(out),256(in)] bf16.
// rr = rr_base + blockIdx.y.  rr<8 -> bf16 into T + rr*t_stride; rr==8 -> fp32 agg = val+bias.
template<int FT>
__launch_bounds__(256)
__global__ void k_gemm(const u16* __restrict__ A, const u16* __restrict__ WtL,
                       u16* __restrict__ T, size_t t_stride, float* __restrict__ agg,
                       const u16* __restrict__ bias, int rr_base, int f0) {
    constexpr int NT = FT / 16;
    int rr = rr_base + blockIdx.y;
    const u16* Bt = WtL + rr * 65536;
    int wave = threadIdx.x >> 6;
    int lane = threadIdx.x & 63;
    int m0 = (blockIdx.x * 4 + wave) * 16;
    if (m0 >= N_NODES) return;
    int mrow = lane & 15, quad = lane >> 4;
    const u16* abase = A + (size_t)(m0 + mrow) * 768 + quad * 8;
    const u16* bbase = Bt + (size_t)(f0 + mrow) * 256 + quad * 8;

    f4 acc[NT];
    #pragma unroll
    for (int t = 0; t < NT; ++t) acc[t] = (f4){0.0f, 0.0f, 0.0f, 0.0f};

    #pragma unroll
    for (int kt = 0; kt < 8; ++kt) {
        bf8 a = *(const bf8*)(abase + kt * 32);
        #pragma unroll
        for (int nt = 0; nt < NT; ++nt) {
            bf8 b = *(const bf8*)(bbase + nt * 4096 + kt * 32);
            acc[nt] = __builtin_amdgcn_mfma_f32_16x16x32_bf16(a, b, acc[nt], 0, 0, 0);
        }
    }

    int rq = quad * 4;
    if (rr < 8) {
        u16* C = T + (size_t)rr * t_stride;
        #pragma unroll
        for (int nt = 0; nt < NT; ++nt)
            #pragma unroll
            for (int v = 0; v < 4; ++v)
                C[(size_t)(m0 + rq + v) * FT + nt * 16 + mrow] = f2b(acc[nt][v]);
    } else {
        #pragma unroll
        for (int nt = 0; nt < NT; ++nt)
            #pragma unroll
            for (int v = 0; v < 4; ++v) {
                int of = nt * 16 + mrow;
                agg[(size_t)(m0 + rq + v) * FT + of] = acc[nt][v] + b2f(bias[f0 + of]);
            }
    }
}

// ---------------- gather (big path): all relations in one pass, no atomics ----------------
// block = dst node; T layout [r][node][256]; skey = r*N+src. Fuses root-add + relu + xc write.
__launch_bounds__(256)
__global__ void k_gather_all(const unsigned int* __restrict__ seg,
                             const unsigned int* __restrict__ skey,
                             const float* __restrict__ sw,
                             const u16* __restrict__ T, const float* __restrict__ agg,
                             u16* __restrict__ xc, int colbase) {
    int d = blockIdx.x, f = threadIdx.x;
    unsigned nb = seg[d * 8], ne = seg[d * 8 + 8];
    float a0 = agg[(size_t)d * 256 + f], a1 = 0.0f, a2 = 0.0f, a3 = 0.0f;
    unsigned i = nb;
    for (; i + 4 <= ne; i += 4) {
        a0 += sw[i]     * b2f(T[(size_t)skey[i]     * 256 + f]);
        a1 += sw[i + 1] * b2f(T[(size_t)skey[i + 1] * 256 + f]);
        a2 += sw[i + 2] * b2f(T[(size_t)skey[i + 2] * 256 + f]);
        a3 += sw[i + 3] * b2f(T[(size_t)skey[i + 3] * 256 + f]);
    }
    for (; i < ne; ++i) a0 += sw[i] * b2f(T[(size_t)skey[i] * 256 + f]);
    float v = (a0 + a1) + (a2 + a3);
    v = v > 0.0f ? v : 0.0f;
    xc[(size_t)d * 768 + colbase + f] = f2b(v);
}

// ---------------- gather (fallback): one relation, FT-wide tile, no atomics ----------------
template<int FT>
__global__ void k_gather_one(const unsigned int* __restrict__ seg,
                             const unsigned int* __restrict__ skey,
                             const float* __restrict__ inv,
                             const u16* __restrict__ T, float* __restrict__ agg, int r) {
    int d = blockIdx.x, f = threadIdx.x;
    unsigned nb = seg[d * 8 + r], ne = seg[d * 8 + r + 1];
    if (nb == ne) return;
    float acc = 0.0f;
    for (unsigned i = nb; i < ne; ++i) {
        unsigned srcn = skey[i] - (unsigned)(r * N_NODES);
        acc += b2f(T[(size_t)srcn * FT + f]);
    }
    agg[(size_t)d * FT + f] += inv[d * 8 + r] * acc;
}

template<int FT>
__global__ void k_finalize(const float* __restrict__ agg, u16* __restrict__ xc, int colbase) {
    int i = blockIdx.x * 256 + threadIdx.x;
    if (i >= N_NODES * FT) return;
    int n = i / FT, of = i % FT;
    float v = agg[i];
    v = v > 0.0f ? v : 0.0f;
    xc[(size_t)n * 768 + colbase + of] = f2b(v);
}

// ---------------- weight-prep transposes ----------------
__global__ void k_transpose(const void* __restrict__ conv_W, const void* __restrict__ conv_root,
                            u16* __restrict__ Wt, const unsigned int* __restrict__ flag) {
    int idx = blockIdx.x * 256 + threadIdx.x;      // ((l*9+rr)*256 + o)*256 + i
    if (idx >= 3 * 9 * 256 * 256) return;
    bool f32 = (*flag != 0u);
    int i = idx & 255;
    int o = (idx >> 8) & 255;
    int lr = idx >> 16;
    int l = lr / 9, rr = lr % 9;
    u16 v;
    if (rr < 8) v = load_cvt(conv_W, (size_t)(((l * 8 + rr) * 256 + i) << 8) + o, f32);
    else        v = load_cvt(conv_root, (size_t)(((l * 256 + i) << 8) + o), f32);
    Wt[idx] = v;
}
__global__ void k_thh(const void* __restrict__ W_hh, u16* __restrict__ whh_t,
                      const unsigned int* __restrict__ flag) {
    int idx = blockIdx.x * 256 + threadIdx.x;      // 262144
    if (idx >= 1024 * 256) return;
    int j = idx >> 8, i = idx & 255;
    whh_t[((i >> 3) << 13) + (j << 3) + (i & 7)] = load_cvt(W_hh, idx, *flag != 0u);
}

// ---------------- pool scorer ----------------
__global__ void k_pool(const u16* __restrict__ xc, const u16* __restrict__ parms,
                       float* __restrict__ p, float* __restrict__ score) {
    int wid = blockIdx.x * 4 + (threadIdx.x >> 6);
    if (wid >= N_NODES * 9) return;
    int n = wid / 9, rr = wid % 9;
    int lane = threadIdx.x & 63;
    const u16* xr = xc + (size_t)n * 768;
    const u16* w = (rr < 8) ? (parms + P_POOL_W + rr * 768) : (parms + P_POOL_ROOT);
    float s = 0.0f;
    #pragma unroll
    for (int q = 0; q < 12; ++q) { int f = lane + 64 * q; s += b2f(xr[f]) * b2f(w[f]); }
    s = wred(s);
    if (lane == 0) {
        if (rr < 8) p[rr * N_NODES + n] = s;
        else        score[n] = s + b2f(parms[P_POOL_BIAS]);
    }
}
__global__ void k_scatter_pool(const int* __restrict__ src, const int* __restrict__ dst,
                               const int* __restrict__ et, const float* __restrict__ inv,
                               const float* __restrict__ p, float* __restrict__ score) {
    int e = blockIdx.x * 256 + threadIdx.x;
    if (e >= N_EDGES) return;
    int r = et[e] & 7;
    unsigned s = (unsigned)src[e]; if (s >= N_NODES) s = 0;
    unsigned d = (unsigned)dst[e]; if (d >= N_NODES) d = 0;
    atomicAdd(&score[d], inv[d * 8 + r] * p[r * N_NODES + s]);
}

// ---------------- per-graph top-K + weighted-mean readout ----------------
__launch_bounds__(256)
__global__ void k_topk(const float* __restrict__ score, const u16* __restrict__ xc,
                       float* __restrict__ readout) {
    __shared__ unsigned long long keys[512];
    __shared__ float vals[512];
    int g = blockIdx.x, tid = threadIdx.x;
    for (int i = tid; i < 512; i += 256) {
        unsigned long long key;
        float v = 0.0f;
        if (i < NPG) {
            v = tanhf(score[g * NPG + i]);
            unsigned int u = __float_as_uint(v);
            u = (u & 0x80000000u) ? ~u : (u | 0x80000000u);  // monotone map
            u = ~u;                                          // descending score
            key = ((unsigned long long)u << 32) | (unsigned int)i;
        } else {
            key = 0xFFFFFFFFFFFFFFFFull;
        }
        keys[i] = key;
        vals[i] = v;
    }
    __syncthreads();
    for (int k = 2; k <= 512; k <<= 1)
        for (int j = k >> 1; j > 0; j >>= 1) {
            for (int i = tid; i < 512; i += 256) {
                int ixj = i ^ j;
                if (ixj > i) {
                    bool up = ((i & k) == 0);
                    unsigned long long a = keys[i], b = keys[ixj];
                    if ((a > b) == up) { keys[i] = b; keys[ixj] = a; }
                }
            }
            __syncthreads();
        }
    float a0 = 0.0f, a1 = 0.0f, a2 = 0.0f;
    for (int jj = 0; jj < KTOP; ++jj) {
        int idx = (int)(keys[jj] & 511u);
        if (idx >= NPG) continue;                            // safety: never OOB
        float v = vals[idx];
        const u16* xr = xc + (size_t)(g * NPG + idx) * 768;
        a0 += v * b2f(xr[tid]);
        a1 += v * b2f(xr[tid + 256]);
        a2 += v * b2f(xr[tid + 512]);
    }
    const float sc = 1.0f / (float)KTOP;
    readout[(size_t)g * 768 + tid]       = a0 * sc;
    readout[(size_t)g * 768 + tid + 256] = a1 * sc;
    readout[(size_t)g * 768 + tid + 512] = a2 * sc;
}

// ---------------- fc1 + LSTM input precompute ----------------
__global__ void k_fc1(const float* __restrict__ readout, const u16* __restrict__ parms,
                      float* __restrict__ h1) {
    int wid = blockIdx.x * 4 + (threadIdx.x >> 6);
    if (wid >= NGRAPH * 256) return;
    int g = wid >> 8, o = wid & 255, lane = threadIdx.x & 63;
    const float* rr = readout + (size_t)g * 768;
    const u16* w = parms + P_FC1_W + (size_t)o * 768;
    float s = 0.0f;
    #pragma unroll
    for (int q = 0; q < 12; ++q) { int f = lane + 64 * q; s += rr[f] * b2f(w[f]); }
    s = wred(s);
    if (lane == 0) { s += b2f(parms[P_FC1_B + o]); h1[g * 256 + o] = s > 0.0f ? s : 0.0f; }
}
__global__ void k_gx(const float* __restrict__ h1, const u16* __restrict__ parms,
                     float* __restrict__ gx) {
    int wid = blockIdx.x * 4 + (threadIdx.x >> 6);
    if (wid >= NGRAPH * 1024) return;
    int t = wid >> 10, j = wid & 1023, lane = threadIdx.x & 63;
    const float* xr = h1 + t * 256;
    const u16* w = parms + P_W_IH + (size_t)j * 256;
    float s = 0.0f;
    #pragma unroll
    for (int q = 0; q < 4; ++q) { int f = lane + 64 * q; s += xr[f] * b2f(w[f]); }
    s = wred(s);
    if (lane == 0) gx[t * 1024 + j] = s + b2f(parms[P_B_IH + j]) + b2f(parms[P_B_HH + j]);
}

// ---------------- sequential LSTM (single block) + fc2 + log_softmax ----------------
__launch_bounds__(1024)
__global__ void k_lstm(const float* __restrict__ gx, const u16* __restrict__ whh_t,
                       const u16* __restrict__ parms, void* __restrict__ out,
                       const unsigned int* __restrict__ flag) {
    __shared__ float hs[256];
    __shared__ float gs[1024];
    __shared__ float red[2];
    int tid = threadIdx.x;
    if (tid < 256) hs[tid] = 0.0f;
    float c = 0.0f;
    __syncthreads();
    for (int t = 0; t < NGRAPH; ++t) {
        float g = gx[t * 1024 + tid];
        #pragma unroll 4
        for (int ib = 0; ib < 32; ++ib) {
            bf8 wv = *(const bf8*)(whh_t + (ib << 13) + (tid << 3));
            #pragma unroll
            for (int q = 0; q < 8; ++q) g += b2f((u16)wv[q]) * hs[ib * 8 + q];
        }
        gs[tid] = g;
        __syncthreads();
        if (tid < 256) {
            float gi = 1.0f / (1.0f + expf(-gs[tid]));
            float gf = 1.0f / (1.0f + expf(-gs[256 + tid]));
            float gg = tanhf(gs[512 + tid]);
            float go = 1.0f / (1.0f + expf(-gs[768 + tid]));
            c = gf * c + gi * gg;
            hs[tid] = go * tanhf(c);
        }
        __syncthreads();
    }
    if (tid < 128) {
        int cls = tid >> 6, lane = tid & 63;
        float s = 0.0f;
        #pragma unroll
        for (int q = 0; q < 4; ++q) {
            int d = lane + 64 * q;
            s += hs[d] * b2f(parms[P_FC2_W + cls * 256 + d]);
        }
        s = wred(s);
        if (lane == 0) red[cls] = s + b2f(parms[P_FC2_B + cls]);
    }
    __syncthreads();
    if (tid == 0) {
        float l0 = red[0], l1 = red[1];
        float m = fmaxf(l0, l1);
        float lse = m + logf(expf(l0 - m) + expf(l1 - m));
        float o0 = l0 - lse, o1 = l1 - lse;
        if (*flag) { ((float*)out)[0] = o0; ((float*)out)[1] = o1; }
        else       { ((u16*)out)[0] = f2b(o0); ((u16*)out)[1] = f2b(o1); }
    }
}

// ---------------- workspace plan ----------------
struct WS {
    unsigned int* flag; unsigned int* cnt; float* inv; unsigned int* seg; unsigned int* ctr;
    unsigned int* skey; float* sw; unsigned int* bsum;
    u16* Wt; u16* t; float* agg; u16* xc; float* p; float* score;
    float* readout; float* h1; float* gx; u16* whh_t; u16* parms;
    size_t need;
};
// FT==0 means the big (all-relations) path
static WS plan(char* base, int FT) {
    WS w; size_t off = 0;
    auto take = [&](size_t bytes) -> char* {
        char* p = base + off; off += (bytes + 255) & ~(size_t)255; return p;
    };
    size_t t_elems   = FT ? (size_t)N_NODES * FT : (size_t)NM * 8;
    size_t agg_elems = FT ? (size_t)N_NODES * FT : (size_t)NM;
    w.flag    = (unsigned int*)take(256);
    w.cnt     = (unsigned int*)take((size_t)NSEG * 4);
    w.inv     = (float*)take((size_t)NSEG * 4);
    w.seg     = (unsigned int*)take((size_t)(NSEG + 1) * 4);
    w.ctr     = (unsigned int*)take((size_t)NSEG * 4);
    w.skey    = (unsigned int*)take((size_t)N_EDGES * 4);
    w.sw      = (float*)take((size_t)N_EDGES * 4);
    w.bsum    = (unsigned int*)take(1024 * 4);
    w.Wt      = (u16*)take((size_t)27 * 65536 * 2);
    w.t       = (u16*)take(t_elems * 2);
    w.agg     = (float*)take(agg_elems * 4);
    w.xc      = (u16*)take((size_t)N_NODES * 768 * 2);
    w.p       = (float*)take((size_t)8 * N_NODES * 4);
    w.score   = (float*)take((size_t)N_NODES * 4);
    w.readout = (float*)take((size_t)NGRAPH * 768 * 4);
    w.h1      = (float*)take((size_t)NGRAPH * 256 * 4);
    w.gx      = (float*)take((size_t)NGRAPH * 1024 * 4);
    w.whh_t   = (u16*)take((size_t)1024 * 256 * 2);
    w.parms   = (u16*)take((size_t)P_TOTAL * 2);
    w.need = off;
    return w;
}

static void run_layers_all(const WS& w, hipStream_t stream) {
    const int gemm_gx = 313;
    for (int l = 0; l < 3; ++l) {
        const u16* A = w.xc + (l == 0 ? 512 : (l - 1) * 256);
        const u16* WtL = w.Wt + (size_t)l * 9 * 65536;
        const u16* bias = w.parms + P_CONV_BIAS + l * 256;
        k_gemm<256><<<dim3(gemm_gx, 9), 256, 0, stream>>>(A, WtL, w.t, (size_t)NM,
                                                          w.agg, bias, 0, 0);
        k_gather_all<<<N_NODES, 256, 0, stream>>>(w.seg, w.skey, w.sw, w.t, w.agg,
                                                  w.xc, l * 256);
    }
}

template<int FT>
static void run_layers_ft(const WS& w, hipStream_t stream) {
    const int gemm_gx = 313;
    const int fin_gx = (N_NODES * FT + 255) / 256;
    for (int l = 0; l < 3; ++l) {
        const u16* A = w.xc + (l == 0 ? 512 : (l - 1) * 256);
        const u16* WtL = w.Wt + (size_t)l * 9 * 65536;
        const u16* bias = w.parms + P_CONV_BIAS + l * 256;
        for (int f0 = 0; f0 < 256; f0 += FT) {
            k_gemm<FT><<<gemm_gx, 256, 0, stream>>>(A, WtL, w.t, 0, w.agg, bias, 8, f0);
            for (int r = 0; r < 8; ++r) {
                k_gemm<FT><<<gemm_gx, 256, 0, stream>>>(A, WtL, w.t, 0, w.agg, bias, r, f0);
                k_gather_one<FT><<<N_NODES, FT, 0, stream>>>(w.seg, w.skey, w.inv,
                                                             w.t, w.agg, r);
            }
            k_finalize<FT><<<fin_gx, 256, 0, stream>>>(w.agg, w.xc, l * 256 + f0);
        }
    }
}

extern "C" void kernel_launch(void* const* d_in, const int* in_sizes, int n_in,
                              void* d_out, int out_size, void* d_ws, size_t ws_size,
                              hipStream_t stream) {
    (void)in_sizes; (void)n_in; (void)out_size;
    const void* x        = d_in[0];
    const int* edge_index= (const int*)d_in[1];
    const int* edge_attr = (const int*)d_in[2];
    const void* conv_W   = d_in[4];
    const void* conv_root= d_in[5];
    const void* conv_bias= d_in[6];
    const void* pool_W   = d_in[7];
    const void* pool_root= d_in[8];
    const void* pool_bias= d_in[9];
    const void* fc1_W    = d_in[10];
    const void* fc1_b    = d_in[11];
    const void* W_ih     = d_in[12];
    const void* W_hh     = d_in[13];
    const void* b_ih     = d_in[14];
    const void* b_hh     = d_in[15];
    const void* fc2_W    = d_in[16];
    const void* fc2_b    = d_in[17];

    const int* e_src = edge_index;
    const int* e_dst = edge_index + N_EDGES;

    // pick path by ws_size (host-side, deterministic): 0 = big all-relations path
    int FT = 64;
    if (plan((char*)d_ws, 0).need <= ws_size)        FT = 0;
    else if (plan((char*)d_ws, 256).need <= ws_size) FT = 256;
    else if (plan((char*)d_ws, 128).need <= ws_size) FT = 128;
    WS w = plan((char*)d_ws, FT);

    // dtype detect (bf16 vs fp32 inputs)
    k_zero_u32<<<1, 256, 0, stream>>>(w.flag, 64);
    k_detect1<<<64, 256, 0, stream>>>((const u16*)x, 1 << 20, w.flag);
    k_detect2<<<1, 1, 0, stream>>>(w.flag);

    // degree counts, inverse means, edge sort
    k_zero_u32<<<(NSEG + 255) / 256, 256, 0, stream>>>(w.cnt, NSEG);
    k_count<<<1250, 256, 0, stream>>>(e_dst, edge_attr, w.cnt);
    k_inv<<<(NSEG + 255) / 256, 256, 0, stream>>>(w.cnt, w.inv, NSEG);
    k_scan1<<<625, 256, 0, stream>>>(w.cnt, w.seg, w.bsum);
    k_scan2<<<1, 1024, 0, stream>>>(w.bsum, 625);
    k_scan3<<<(NSEG + 255) / 256, 256, 0, stream>>>(w.seg, w.bsum);
    k_zero_u32<<<(NSEG + 255) / 256, 256, 0, stream>>>(w.ctr, NSEG);
    k_place<<<1250, 256, 0, stream>>>(e_src, e_dst, edge_attr, w.seg, w.ctr, w.inv,
                                      w.skey, w.sw);

    // canonicalize params to bf16
    auto cvt = [&](const void* src, int parm_off, int n) {
        k_convert<<<(n + 255) / 256, 256, 0, stream>>>(src, w.parms + parm_off, n, w.flag);
    };
    cvt(conv_bias, P_CONV_BIAS, 768);
    cvt(pool_W,    P_POOL_W,    6144);
    cvt(pool_root, P_POOL_ROOT, 768);
    cvt(pool_bias, P_POOL_BIAS, 1);
    cvt(fc1_W,     P_FC1_W,     196608);
    cvt(fc1_b,     P_FC1_B,     256);
    cvt(W_ih,      P_W_IH,      262144);
    cvt(b_ih,      P_B_IH,      1024);
    cvt(b_hh,      P_B_HH,      1024);
    cvt(fc2_W,     P_FC2_W,     512);
    cvt(fc2_b,     P_FC2_B,     2);

    k_stage_x<<<20000, 256, 0, stream>>>(x, w.xc, w.flag);
    k_transpose<<<6912, 256, 0, stream>>>(conv_W, conv_root, w.Wt, w.flag);
    k_thh<<<1024, 256, 0, stream>>>(W_hh, w.whh_t, w.flag);

    if (FT == 0)        run_layers_all(w, stream);
    else if (FT == 256) run_layers_ft<256>(w, stream);
    else if (FT == 128) run_layers_ft<128>(w, stream);
    else                run_layers_ft<64>(w, stream);

    k_pool<<<45000, 256, 0, stream>>>(w.xc, w.parms, w.p, w.score);
    k_scatter_pool<<<1250, 256, 0, stream>>>(e_src, e_dst, edge_attr, w.inv, w.p, w.score);
    k_topk<<<NGRAPH, 256, 0, stream>>>(w.score, w.xc, w.readout);
    k_fc1<<<2560, 256, 0, stream>>>(w.readout, w.parms, w.h1);
    k_gx<<<10240, 256, 0, stream>>>(w.h1, w.parms, w.gx);
    k_lstm<<<1, 1024, 0, stream>>>(w.gx, w.whh_t, w.parms, d_out, w.flag);
}

// Round 6
// 1091.789 us; speedup vs baseline: 2.4655x; 1.1450x over previous
//
#include <hip/hip_runtime.h>

typedef unsigned short u16;
typedef short bf8 __attribute__((ext_vector_type(8)));
typedef float f4 __attribute__((ext_vector_type(4)));
typedef _Float16 h2v __attribute__((ext_vector_type(2)));
typedef __fp16 g2v __attribute__((ext_vector_type(2)));

#define N_NODES 20000
#define N_EDGES 320000
#define NGRAPH 40
#define NPG 500
#define KTOP 250
#define NSEG (N_NODES * 8)
#define NM (N_NODES * 256)

// parms arena offsets (u16 elements)
#define P_CONV_BIAS 0
#define P_POOL_W    768
#define P_POOL_ROOT 6912
#define P_POOL_BIAS 7680
#define P_FC1_W     7688
#define P_FC1_B     204296
#define P_W_IH      204552
#define P_B_IH      466696
#define P_B_HH      467720
#define P_FC2_W     468744
#define P_FC2_B     469256
#define P_TOTAL     469264

__device__ __forceinline__ float b2f(u16 u) {
    union { unsigned int i; float f; } v; v.i = ((unsigned int)u) << 16; return v.f;
}
__device__ __forceinline__ u16 f2b(float f) {
    union { float f; unsigned int i; } v; v.f = f;
    unsigned int x = v.i;
    return (u16)((x + 0x7fffu + ((x >> 16) & 1u)) >> 16);
}
__device__ __forceinline__ float wred(float s) {
    #pragma unroll
    for (int off = 32; off > 0; off >>= 1) s += __shfl_down(s, off);
    return s;
}
__device__ __forceinline__ float fdot2u(unsigned a, unsigned b, float c) {
#if __has_builtin(__builtin_amdgcn_fdot2)
    union { unsigned u; h2v h; } ua, ub; ua.u = a; ub.u = b;
    return __builtin_amdgcn_fdot2(ua.h, ub.h, c, false);
#else
    union { unsigned u; g2v h; } ua, ub; ua.u = a; ub.u = b;
    return c + (float)ua.h[0] * (float)ub.h[0] + (float)ua.h[1] * (float)ub.h[1];
#endif
}
__device__ __forceinline__ unsigned packh2(float a, float b) {
    g2v h = __builtin_amdgcn_cvt_pkrtz(a, b);
    union { g2v h; unsigned u; } v; v.h = h; return v.u;
}

// ---------------- init: zero flag + cnt + ctr ----------------
__global__ void k_init(unsigned int* __restrict__ flag, unsigned int* __restrict__ cnt,
                       unsigned int* __restrict__ ctr) {
    int i = blockIdx.x * 256 + threadIdx.x;
    if (i < 64) flag[i] = 0u;
    if (i < NSEG) { cnt[i] = 0u; ctr[i] = 0u; }
}

// ---------------- dtype detection (parallel) ----------------
__global__ void k_detect1(const u16* __restrict__ xr, int n, unsigned int* __restrict__ fb) {
    unsigned int local = 0;
    for (int i = blockIdx.x * 256 + threadIdx.x; i < n; i += 64 * 256) {
        unsigned int u = xr[i];
        if (((u >> 7) & 0xFFu) == 0xFFu) local++;
    }
    local = (unsigned int)wred((float)local);
    if ((threadIdx.x & 63) == 0 && local) atomicAdd(&fb[1], local);
}
__global__ void k_detect2(unsigned int* __restrict__ fb) {
    fb[0] = (fb[1] > 8u) ? 1u : 0u;
}

__device__ __forceinline__ u16 load_cvt(const void* src, size_t i, bool f32) {
    return f32 ? f2b(((const float*)src)[i]) : ((const u16*)src)[i];
}

// ---------------- one-shot param canonicalization (11 tensors -> bf16 arena) ----------------
__global__ void k_cvt_all(const void* conv_bias, const void* pool_W, const void* pool_root,
                          const void* pool_bias, const void* fc1_W, const void* fc1_b,
                          const void* W_ih, const void* b_ih, const void* b_hh,
                          const void* fc2_W, const void* fc2_b,
                          u16* __restrict__ parms, const unsigned int* __restrict__ flag) {
    int i = blockIdx.x * 256 + threadIdx.x;
    if (i >= P_TOTAL) return;
    bool f32 = (*flag != 0u);
    u16 v;
    if      (i < P_CONV_BIAS + 768)    v = load_cvt(conv_bias, i - P_CONV_BIAS, f32);
    else if (i < P_POOL_W + 6144)      v = load_cvt(pool_W,    i - P_POOL_W, f32);
    else if (i < P_POOL_ROOT + 768)    v = load_cvt(pool_root, i - P_POOL_ROOT, f32);
    else if (i < P_POOL_BIAS + 1)      v = load_cvt(pool_bias, i - P_POOL_BIAS, f32);
    else if (i < P_FC1_W && i >= P_POOL_BIAS) return;        // alignment gap
    else if (i < P_FC1_W + 196608)     v = load_cvt(fc1_W,    i - P_FC1_W, f32);
    else if (i < P_FC1_B + 256)        v = load_cvt(fc1_b,    i - P_FC1_B, f32);
    else if (i < P_W_IH + 262144)      v = load_cvt(W_ih,     i - P_W_IH, f32);
    else if (i < P_B_IH + 1024)        v = load_cvt(b_ih,     i - P_B_IH, f32);
    else if (i < P_B_HH + 1024)        v = load_cvt(b_hh,     i - P_B_HH, f32);
    else if (i < P_FC2_W + 512)        v = load_cvt(fc2_W,    i - P_FC2_W, f32);
    else if (i < P_FC2_B + 2)          v = load_cvt(fc2_b,    i - P_FC2_B, f32);
    else return;
    parms[i] = v;
}

// stage x (canonical bf16) into xc[:, 512:768]
__global__ void k_stage_x(const void* __restrict__ src, u16* __restrict__ xc,
                          const unsigned int* __restrict__ flag) {
    int i = blockIdx.x * 256 + threadIdx.x;
    if (i >= N_NODES * 256) return;
    u16 v = load_cvt(src, i, *flag != 0u);
    int n = i >> 8, f = i & 255;
    xc[(size_t)n * 768 + 512 + f] = v;
}

// ---------------- degree counts ----------------
__global__ void k_count(const int* __restrict__ dst, const int* __restrict__ et,
                        unsigned int* __restrict__ cnt) {
    int e = blockIdx.x * 256 + threadIdx.x;
    if (e < N_EDGES) {
        unsigned d = (unsigned)dst[e]; if (d >= N_NODES) d = 0;
        unsigned r = (unsigned)et[e] & 7u;
        atomicAdd(&cnt[d * 8 + r], 1u);
    }
}
__global__ void k_inv(const unsigned int* __restrict__ cnt, float* __restrict__ inv, int n) {
    int i = blockIdx.x * 256 + threadIdx.x;
    if (i < n) {
        unsigned int c = cnt[i];
        inv[i] = 1.0f / (float)(c < 1u ? 1u : c);
    }
}

// ---------------- prefix scan (exclusive) over cnt[160000] ----------------
__global__ void k_scan1(const unsigned int* __restrict__ cnt, unsigned int* __restrict__ seg,
                        unsigned int* __restrict__ bsum) {
    __shared__ unsigned int s[256];
    int t = threadIdx.x, i = blockIdx.x * 256 + t;
    unsigned int v = (i < NSEG) ? cnt[i] : 0u;
    s[t] = v;
    __syncthreads();
    for (int off = 1; off < 256; off <<= 1) {
        unsigned int add = (t >= off) ? s[t - off] : 0u;
        __syncthreads();
        s[t] += add;
        __syncthreads();
    }
    if (i < NSEG) seg[i] = s[t] - v;
    if (t == 255) bsum[blockIdx.x] = s[255];
}
__global__ void k_scan2(unsigned int* __restrict__ bsum, int nb) {
    __shared__ unsigned int s[1024];
    int t = threadIdx.x;
    unsigned int v = (t < nb) ? bsum[t] : 0u;
    s[t] = v;
    __syncthreads();
    for (int off = 1; off < 1024; off <<= 1) {
        unsigned int add = (t >= off) ? s[t - off] : 0u;
        __syncthreads();
        s[t] += add;
        __syncthreads();
    }
    if (t < nb) bsum[t] = s[t] - v;
}
__global__ void k_scan3(unsigned int* __restrict__ seg, const unsigned int* __restrict__ bsum) {
    int i = blockIdx.x * 256 + threadIdx.x;
    if (i < NSEG) seg[i] += bsum[i >> 8];
    if (i == 0) seg[NSEG] = N_EDGES;
}
__global__ void k_place(const int* __restrict__ src, const int* __restrict__ dst,
                        const int* __restrict__ et, const unsigned int* __restrict__ seg,
                        unsigned int* __restrict__ ctr, const float* __restrict__ inv,
                        unsigned int* __restrict__ skey, float* __restrict__ sw) {
    int e = blockIdx.x * 256 + threadIdx.x;
    if (e >= N_EDGES) return;
    unsigned s = (unsigned)src[e]; if (s >= N_NODES) s = 0;
    unsigned d = (unsigned)dst[e]; if (d >= N_NODES) d = 0;
    unsigned r = (unsigned)et[e] & 7u;
    unsigned key = d * 8 + r;
    unsigned pos = seg[key] + atomicAdd(&ctr[key], 1u);
    skey[pos] = r * N_NODES + s;
    sw[pos] = inv[key];
}

// ---------------- RGCN GEMM ----------------
template<int FT>
__launch_bounds__(256)
__global__ void k_gemm(const u16* __restrict__ A, const u16* __restrict__ WtL,
                       u16* __restrict__ T, size_t t_stride, float* __restrict__ agg,
                       const u16* __restrict__ bias, int rr_base, int f0) {
    constexpr int NT = FT / 16;
    int rr = rr_base + blockIdx.y;
    const u16* Bt = WtL + rr * 65536;
    int wave = threadIdx.x >> 6;
    int lane = threadIdx.x & 63;
    int m0 = (blockIdx.x * 4 + wave) * 16;
    if (m0 >= N_NODES) return;
    int mrow = lane & 15, quad = lane >> 4;
    const u16* abase = A + (size_t)(m0 + mrow) * 768 + quad * 8;
    const u16* bbase = Bt + (size_t)(f0 + mrow) * 256 + quad * 8;

    f4 acc[NT];
    #pragma unroll
    for (int t = 0; t < NT; ++t) acc[t] = (f4){0.0f, 0.0f, 0.0f, 0.0f};

    #pragma unroll
    for (int kt = 0; kt < 8; ++kt) {
        bf8 a = *(const bf8*)(abase + kt * 32);
        #pragma unroll
        for (int nt = 0; nt < NT; ++nt) {
            bf8 b = *(const bf8*)(bbase + nt * 4096 + kt * 32);
            acc[nt] = __builtin_amdgcn_mfma_f32_16x16x32_bf16(a, b, acc[nt], 0, 0, 0);
        }
    }

    int rq = quad * 4;
    if (rr < 8) {
        u16* C = T + (size_t)rr * t_stride;
        #pragma unroll
        for (int nt = 0; nt < NT; ++nt)
            #pragma unroll
            for (int v = 0; v < 4; ++v)
                C[(size_t)(m0 + rq + v) * FT + nt * 16 + mrow] = f2b(acc[nt][v]);
    } else {
        #pragma unroll
        for (int nt = 0; nt < NT; ++nt)
            #pragma unroll
            for (int v = 0; v < 4; ++v) {
                int of = nt * 16 + mrow;
                agg[(size_t)(m0 + rq + v) * FT + of] = acc[nt][v] + b2f(bias[f0 + of]);
            }
    }
}

// ---------------- gather (big path) ----------------
__launch_bounds__(256)
__global__ void k_gather_all(const unsigned int* __restrict__ seg,
                             const unsigned int* __restrict__ skey,
                             const float* __restrict__ sw,
                             const u16* __restrict__ T, const float* __restrict__ agg,
                             u16* __restrict__ xc, int colbase) {
    int d = blockIdx.x, f = threadIdx.x;
    unsigned nb = seg[d * 8], ne = seg[d * 8 + 8];
    float a0 = agg[(size_t)d * 256 + f], a1 = 0.0f, a2 = 0.0f, a3 = 0.0f;
    unsigned i = nb;
    for (; i + 4 <= ne; i += 4) {
        a0 += sw[i]     * b2f(T[(size_t)skey[i]     * 256 + f]);
        a1 += sw[i + 1] * b2f(T[(size_t)skey[i + 1] * 256 + f]);
        a2 += sw[i + 2] * b2f(T[(size_t)skey[i + 2] * 256 + f]);
        a3 += sw[i + 3] * b2f(T[(size_t)skey[i + 3] * 256 + f]);
    }
    for (; i < ne; ++i) a0 += sw[i] * b2f(T[(size_t)skey[i] * 256 + f]);
    float v = (a0 + a1) + (a2 + a3);
    v = v > 0.0f ? v : 0.0f;
    xc[(size_t)d * 768 + colbase + f] = f2b(v);
}

// ---------------- gather (fallback): one relation, FT tile ----------------
template<int FT>
__global__ void k_gather_one(const unsigned int* __restrict__ seg,
                             const unsigned int* __restrict__ skey,
                             const float* __restrict__ inv,
                             const u16* __restrict__ T, float* __restrict__ agg, int r) {
    int d = blockIdx.x, f = threadIdx.x;
    unsigned nb = seg[d * 8 + r], ne = seg[d * 8 + r + 1];
    if (nb == ne) return;
    float acc = 0.0f;
    for (unsigned i = nb; i < ne; ++i) {
        unsigned srcn = skey[i] - (unsigned)(r * N_NODES);
        acc += b2f(T[(size_t)srcn * FT + f]);
    }
    agg[(size_t)d * FT + f] += inv[d * 8 + r] * acc;
}

template<int FT>
__global__ void k_finalize(const float* __restrict__ agg, u16* __restrict__ xc, int colbase) {
    int i = blockIdx.x * 256 + threadIdx.x;
    if (i >= N_NODES * FT) return;
    int n = i / FT, of = i % FT;
    float v = agg[i];
    v = v > 0.0f ? v : 0.0f;
    xc[(size_t)n * 768 + colbase + of] = f2b(v);
}

// ---------------- weight-prep ----------------
__global__ void k_transpose(const void* __restrict__ conv_W, const void* __restrict__ conv_root,
                            u16* __restrict__ Wt, const unsigned int* __restrict__ flag) {
    int idx = blockIdx.x * 256 + threadIdx.x;
    if (idx >= 3 * 9 * 256 * 256) return;
    bool f32 = (*flag != 0u);
    int i = idx & 255;
    int o = (idx >> 8) & 255;
    int lr = idx >> 16;
    int l = lr / 9, rr = lr % 9;
    u16 v;
    if (rr < 8) v = load_cvt(conv_W, (size_t)(((l * 8 + rr) * 256 + i) << 8) + o, f32);
    else        v = load_cvt(conv_root, (size_t)(((l * 256 + i) << 8) + o), f32);
    Wt[idx] = v;
}
// W_hh [j][i] -> packed f16 pairs whh2[i2][j], i2 = i/2
__global__ void k_whh2(const void* __restrict__ W_hh, unsigned int* __restrict__ whh2,
                       const unsigned int* __restrict__ flag) {
    int idx = blockIdx.x * 256 + threadIdx.x;     // 128*1024
    if (idx >= 128 * 1024) return;
    int i2 = idx >> 10, j = idx & 1023;
    bool f32 = (*flag != 0u);
    float a, b;
    if (f32) {
        a = ((const float*)W_hh)[j * 256 + 2 * i2];
        b = ((const float*)W_hh)[j * 256 + 2 * i2 + 1];
    } else {
        a = b2f(((const u16*)W_hh)[j * 256 + 2 * i2]);
        b = b2f(((const u16*)W_hh)[j * 256 + 2 * i2 + 1]);
    }
    whh2[idx] = packh2(a, b);
}

// ---------------- pool scorer: one wave per node, all 9 dots fused ----------------
__launch_bounds__(256)
__global__ void k_pool(const u16* __restrict__ xc, const u16* __restrict__ parms,
                       float* __restrict__ p, float* __restrict__ score) {
    int n = blockIdx.x * 4 + (threadIdx.x >> 6);
    if (n >= N_NODES) return;
    int lane = threadIdx.x & 63;
    const u16* xr = xc + (size_t)n * 768;
    float acc[9];
    #pragma unroll
    for (int rr = 0; rr < 9; ++rr) acc[rr] = 0.0f;
    #pragma unroll
    for (int q = 0; q < 12; ++q) {
        int f = lane + 64 * q;
        float xv = b2f(xr[f]);
        #pragma unroll
        for (int rr = 0; rr < 8; ++rr)
            acc[rr] += xv * b2f(parms[P_POOL_W + rr * 768 + f]);
        acc[8] += xv * b2f(parms[P_POOL_ROOT + f]);
    }
    #pragma unroll
    for (int rr = 0; rr < 9; ++rr) acc[rr] = wred(acc[rr]);
    if (lane == 0) {
        #pragma unroll
        for (int rr = 0; rr < 8; ++rr) p[rr * N_NODES + n] = acc[rr];
        score[n] = acc[8] + b2f(parms[P_POOL_BIAS]);
    }
}
__global__ void k_scatter_pool(const int* __restrict__ src, const int* __restrict__ dst,
                               const int* __restrict__ et, const float* __restrict__ inv,
                               const float* __restrict__ p, float* __restrict__ score) {
    int e = blockIdx.x * 256 + threadIdx.x;
    if (e >= N_EDGES) return;
    int r = et[e] & 7;
    unsigned s = (unsigned)src[e]; if (s >= N_NODES) s = 0;
    unsigned d = (unsigned)dst[e]; if (d >= N_NODES) d = 0;
    atomicAdd(&score[d], inv[d * 8 + r] * p[r * N_NODES + s]);
}

// ---------------- per-graph top-K sort (indices + weights only) ----------------
__launch_bounds__(256)
__global__ void k_sort(const float* __restrict__ score, unsigned int* __restrict__ topidx,
                       float* __restrict__ topv) {
    __shared__ unsigned long long keys[512];
    __shared__ float vals[512];
    int g = blockIdx.x, tid = threadIdx.x;
    for (int i = tid; i < 512; i += 256) {
        unsigned long long key;
        float v = 0.0f;
        if (i < NPG) {
            v = tanhf(score[g * NPG + i]);
            unsigned int u = __float_as_uint(v);
            u = (u & 0x80000000u) ? ~u : (u | 0x80000000u);
            u = ~u;
            key = ((unsigned long long)u << 32) | (unsigned int)i;
        } else {
            key = 0xFFFFFFFFFFFFFFFFull;
        }
        keys[i] = key;
        vals[i] = v;
    }
    __syncthreads();
    for (int k = 2; k <= 512; k <<= 1)
        for (int j = k >> 1; j > 0; j >>= 1) {
            for (int i = tid; i < 512; i += 256) {
                int ixj = i ^ j;
                if (ixj > i) {
                    bool up = ((i & k) == 0);
                    unsigned long long a = keys[i], b = keys[ixj];
                    if ((a > b) == up) { keys[i] = b; keys[ixj] = a; }
                }
            }
            __syncthreads();
        }
    if (tid < KTOP) {
        int idx = (int)(keys[tid] & 511u);
        topidx[g * 256 + tid] = (unsigned)idx;
        topv[g * 256 + tid] = vals[idx];
    }
}

// ---------------- parallel weighted readout: grid (40, 12), 64 feats/block ----------------
__launch_bounds__(256)
__global__ void k_readout(const unsigned int* __restrict__ topidx,
                          const float* __restrict__ topv,
                          const u16* __restrict__ xc, float* __restrict__ readout) {
    __shared__ unsigned int sidx[KTOP];
    __shared__ float sv[KTOP];
    __shared__ float part[256];
    int g = blockIdx.x, cb = blockIdx.y;
    int tid = threadIdx.x;
    if (tid < KTOP) { sidx[tid] = topidx[g * 256 + tid]; sv[tid] = topv[g * 256 + tid]; }
    __syncthreads();
    int fl = tid & 63, ng = tid >> 6;
    int f = cb * 64 + fl;
    float acc = 0.0f;
    for (int j = ng; j < KTOP; j += 4)
        acc += sv[j] * b2f(xc[(size_t)(g * NPG + sidx[j]) * 768 + f]);
    part[tid] = acc;
    __syncthreads();
    if (tid < 64) {
        float s = part[tid] + part[64 + tid] + part[128 + tid] + part[192 + tid];
        readout[(size_t)g * 768 + cb * 64 + tid] = s * (1.0f / (float)KTOP);
    }
}

// ---------------- fc1 + LSTM input precompute ----------------
__global__ void k_fc1(const float* __restrict__ readout, const u16* __restrict__ parms,
                      float* __restrict__ h1) {
    int wid = blockIdx.x * 4 + (threadIdx.x >> 6);
    if (wid >= NGRAPH * 256) return;
    int g = wid >> 8, o = wid & 255, lane = threadIdx.x & 63;
    const float* rr = readout + (size_t)g * 768;
    const u16* w = parms + P_FC1_W + (size_t)o * 768;
    float s = 0.0f;
    #pragma unroll
    for (int q = 0; q < 12; ++q) { int f = lane + 64 * q; s += rr[f] * b2f(w[f]); }
    s = wred(s);
    if (lane == 0) { s += b2f(parms[P_FC1_B + o]); h1[g * 256 + o] = s > 0.0f ? s : 0.0f; }
}
__global__ void k_gx(const float* __restrict__ h1, const u16* __restrict__ parms,
                     float* __restrict__ gx) {
    int wid = blockIdx.x * 4 + (threadIdx.x >> 6);
    if (wid >= NGRAPH * 1024) return;
    int t = wid >> 10, j = wid & 1023, lane = threadIdx.x & 63;
    const float* xr = h1 + t * 256;
    const u16* w = parms + P_W_IH + (size_t)j * 256;
    float s = 0.0f;
    #pragma unroll
    for (int q = 0; q < 4; ++q) { int f = lane + 64 * q; s += xr[f] * b2f(w[f]); }
    s = wred(s);
    if (lane == 0) gx[t * 1024 + j] = s + b2f(parms[P_B_IH + j]) + b2f(parms[P_B_HH + j]);
}

// ---------------- sequential LSTM: f16-dot2, half of W_hh register-resident ----------------
__launch_bounds__(1024, 4)
__global__ void k_lstm(const float* __restrict__ gx, const unsigned int* __restrict__ whh2,
                       const u16* __restrict__ parms, void* __restrict__ out,
                       const unsigned int* __restrict__ flag) {
    __shared__ float hs[256];
    __shared__ unsigned int hs2[128];
    __shared__ float gs[1024];
    __shared__ float red[2];
    int tid = threadIdx.x;
    unsigned int wreg[64];
    #pragma unroll
    for (int i = 0; i < 64; ++i) wreg[i] = whh2[i * 1024 + tid];
    if (tid < 256) hs[tid] = 0.0f;
    if (tid < 128) hs2[tid] = 0u;
    float c = 0.0f;
    __syncthreads();
    for (int t = 0; t < NGRAPH; ++t) {
        float g = gx[t * 1024 + tid];
        #pragma unroll
        for (int i = 0; i < 64; ++i) g = fdot2u(wreg[i], hs2[i], g);
        #pragma unroll 8
        for (int i = 64; i < 128; ++i) g = fdot2u(whh2[i * 1024 + tid], hs2[i], g);
        gs[tid] = g;
        __syncthreads();
        if (tid < 256) {
            float gi = 1.0f / (1.0f + expf(-gs[tid]));
            float gf = 1.0f / (1.0f + expf(-gs[256 + tid]));
            float gg = tanhf(gs[512 + tid]);
            float go = 1.0f / (1.0f + expf(-gs[768 + tid]));
            c = gf * c + gi * gg;
            float h = go * tanhf(c);
            hs[tid] = h;
            float ho = __shfl(h, (tid & 63) ^ 1);
            if (!(tid & 1)) hs2[tid >> 1] = packh2(h, ho);
        }
        __syncthreads();
    }
    if (tid < 128) {
        int cls = tid >> 6, lane = tid & 63;
        float s = 0.0f;
        #pragma unroll
        for (int q = 0; q < 4; ++q) {
            int d = lane + 64 * q;
            s += hs[d] * b2f(parms[P_FC2_W + cls * 256 + d]);
        }
        s = wred(s);
        if (lane == 0) red[cls] = s + b2f(parms[P_FC2_B + cls]);
    }
    __syncthreads();
    if (tid == 0) {
        float l0 = red[0], l1 = red[1];
        float m = fmaxf(l0, l1);
        float lse = m + logf(expf(l0 - m) + expf(l1 - m));
        float o0 = l0 - lse, o1 = l1 - lse;
        if (*flag) { ((float*)out)[0] = o0; ((float*)out)[1] = o1; }
        else       { ((u16*)out)[0] = f2b(o0); ((u16*)out)[1] = f2b(o1); }
    }
}

// ---------------- workspace plan ----------------
struct WS {
    unsigned int* flag; unsigned int* cnt; float* inv; unsigned int* seg; unsigned int* ctr;
    unsigned int* skey; float* sw; unsigned int* bsum;
    u16* Wt; u16* t; float* agg; u16* xc; float* p; float* score;
    unsigned int* topidx; float* topv;
    float* readout; float* h1; float* gx; unsigned int* whh2; u16* parms;
    size_t need;
};
// FT==0 means the big (all-relations) path
static WS plan(char* base, int FT) {
    WS w; size_t off = 0;
    auto take = [&](size_t bytes) -> char* {
        char* p = base + off; off += (bytes + 255) & ~(size_t)255; return p;
    };
    size_t t_elems   = FT ? (size_t)N_NODES * FT : (size_t)NM * 8;
    size_t agg_elems = FT ? (size_t)N_NODES * FT : (size_t)NM;
    w.flag    = (unsigned int*)take(256);
    w.cnt     = (unsigned int*)take((size_t)NSEG * 4);
    w.inv     = (float*)take((size_t)NSEG * 4);
    w.seg     = (unsigned int*)take((size_t)(NSEG + 1) * 4);
    w.ctr     = (unsigned int*)take((size_t)NSEG * 4);
    w.skey    = (unsigned int*)take((size_t)N_EDGES * 4);
    w.sw      = (float*)take((size_t)N_EDGES * 4);
    w.bsum    = (unsigned int*)take(1024 * 4);
    w.Wt      = (u16*)take((size_t)27 * 65536 * 2);
    w.t       = (u16*)take(t_elems * 2);
    w.agg     = (float*)take(agg_elems * 4);
    w.xc      = (u16*)take((size_t)N_NODES * 768 * 2);
    w.p       = (float*)take((size_t)8 * N_NODES * 4);
    w.score   = (float*)take((size_t)N_NODES * 4);
    w.topidx  = (unsigned int*)take((size_t)NGRAPH * 256 * 4);
    w.topv    = (float*)take((size_t)NGRAPH * 256 * 4);
    w.readout = (float*)take((size_t)NGRAPH * 768 * 4);
    w.h1      = (float*)take((size_t)NGRAPH * 256 * 4);
    w.gx      = (float*)take((size_t)NGRAPH * 1024 * 4);
    w.whh2    = (unsigned int*)take((size_t)128 * 1024 * 4);
    w.parms   = (u16*)take((size_t)P_TOTAL * 2);
    w.need = off;
    return w;
}

static void run_layers_all(const WS& w, hipStream_t stream) {
    const int gemm_gx = 313;
    for (int l = 0; l < 3; ++l) {
        const u16* A = w.xc + (l == 0 ? 512 : (l - 1) * 256);
        const u16* WtL = w.Wt + (size_t)l * 9 * 65536;
        const u16* bias = w.parms + P_CONV_BIAS + l * 256;
        k_gemm<256><<<dim3(gemm_gx, 9), 256, 0, stream>>>(A, WtL, w.t, (size_t)NM,
                                                          w.agg, bias, 0, 0);
        k_gather_all<<<N_NODES, 256, 0, stream>>>(w.seg, w.skey, w.sw, w.t, w.agg,
                                                  w.xc, l * 256);
    }
}

template<int FT>
static void run_layers_ft(const WS& w, hipStream_t stream) {
    const int gemm_gx = 313;
    const int fin_gx = (N_NODES * FT + 255) / 256;
    for (int l = 0; l < 3; ++l) {
        const u16* A = w.xc + (l == 0 ? 512 : (l - 1) * 256);
        const u16* WtL = w.Wt + (size_t)l * 9 * 65536;
        const u16* bias = w.parms + P_CONV_BIAS + l * 256;
        for (int f0 = 0; f0 < 256; f0 += FT) {
            k_gemm<FT><<<gemm_gx, 256, 0, stream>>>(A, WtL, w.t, 0, w.agg, bias, 8, f0);
            for (int r = 0; r < 8; ++r) {
                k_gemm<FT><<<gemm_gx, 256, 0, stream>>>(A, WtL, w.t, 0, w.agg, bias, r, f0);
                k_gather_one<FT><<<N_NODES, FT, 0, stream>>>(w.seg, w.skey, w.inv,
                                                             w.t, w.agg, r);
            }
            k_finalize<FT><<<fin_gx, 256, 0, stream>>>(w.agg, w.xc, l * 256 + f0);
        }
    }
}

extern "C" void kernel_launch(void* const* d_in, const int* in_sizes, int n_in,
                              void* d_out, int out_size, void* d_ws, size_t ws_size,
                              hipStream_t stream) {
    (void)in_sizes; (void)n_in; (void)out_size;
    const void* x        = d_in[0];
    const int* edge_index= (const int*)d_in[1];
    const int* edge_attr = (const int*)d_in[2];
    const void* conv_W   = d_in[4];
    const void* conv_root= d_in[5];
    const void* conv_bias= d_in[6];
    const void* pool_W   = d_in[7];
    const void* pool_root= d_in[8];
    const void* pool_bias= d_in[9];
    const void* fc1_W    = d_in[10];
    const void* fc1_b    = d_in[11];
    const void* W_ih     = d_in[12];
    const void* W_hh     = d_in[13];
    const void* b_ih     = d_in[14];
    const void* b_hh     = d_in[15];
    const void* fc2_W    = d_in[16];
    const void* fc2_b    = d_in[17];

    const int* e_src = edge_index;
    const int* e_dst = edge_index + N_EDGES;

    int FT = 64;
    if (plan((char*)d_ws, 0).need <= ws_size)        FT = 0;
    else if (plan((char*)d_ws, 256).need <= ws_size) FT = 256;
    else if (plan((char*)d_ws, 128).need <= ws_size) FT = 128;
    WS w = plan((char*)d_ws, FT);

    k_init<<<(NSEG + 255) / 256, 256, 0, stream>>>(w.flag, w.cnt, w.ctr);
    k_detect1<<<64, 256, 0, stream>>>((const u16*)x, 1 << 20, w.flag);
    k_detect2<<<1, 1, 0, stream>>>(w.flag);

    k_count<<<1250, 256, 0, stream>>>(e_dst, edge_attr, w.cnt);
    k_inv<<<(NSEG + 255) / 256, 256, 0, stream>>>(w.cnt, w.inv, NSEG);
    k_scan1<<<625, 256, 0, stream>>>(w.cnt, w.seg, w.bsum);
    k_scan2<<<1, 1024, 0, stream>>>(w.bsum, 625);
    k_scan3<<<(NSEG + 255) / 256, 256, 0, stream>>>(w.seg, w.bsum);
    k_place<<<1250, 256, 0, stream>>>(e_src, e_dst, edge_attr, w.seg, w.ctr, w.inv,
                                      w.skey, w.sw);

    k_cvt_all<<<(P_TOTAL + 255) / 256, 256, 0, stream>>>(
        conv_bias, pool_W, pool_root, pool_bias, fc1_W, fc1_b,
        W_ih, b_ih, b_hh, fc2_W, fc2_b, w.parms, w.flag);

    k_stage_x<<<20000, 256, 0, stream>>>(x, w.xc, w.flag);
    k_transpose<<<6912, 256, 0, stream>>>(conv_W, conv_root, w.Wt, w.flag);
    k_whh2<<<512, 256, 0, stream>>>(W_hh, w.whh2, w.flag);

    if (FT == 0)        run_layers_all(w, stream);
    else if (FT == 256) run_layers_ft<256>(w, stream);
    else if (FT == 128) run_layers_ft<128>(w, stream);
    else                run_layers_ft<64>(w, stream);

    k_pool<<<5000, 256, 0, stream>>>(w.xc, w.parms, w.p, w.score);
    k_scatter_pool<<<1250, 256, 0, stream>>>(e_src, e_dst, edge_attr, w.inv, w.p, w.score);
    k_sort<<<NGRAPH, 256, 0, stream>>>(w.score, w.topidx, w.topv);
    k_readout<<<dim3(NGRAPH, 12), 256, 0, stream>>>(w.topidx, w.topv, w.xc, w.readout);
    k_fc1<<<2560, 256, 0, stream>>>(w.readout, w.parms, w.h1);
    k_gx<<<10240, 256, 0, stream>>>(w.h1, w.parms, w.gx);
    k_lstm<<<1, 1024, 0, stream>>>(w.gx, w.whh2, w.parms, d_out, w.flag);
}

// Round 7
// 794.271 us; speedup vs baseline: 3.3890x; 1.3746x over previous
//
#include <hip/hip_runtime.h>

typedef unsigned short u16;
typedef short bf8 __attribute__((ext_vector_type(8)));
typedef float f4 __attribute__((ext_vector_type(4)));
typedef _Float16 h2v __attribute__((ext_vector_type(2)));
typedef __fp16 g2v __attribute__((ext_vector_type(2)));

#define N_NODES 20000
#define N_EDGES 320000
#define NGRAPH 40
#define NPG 500
#define KTOP 250
#define NSEG (N_NODES * 8)
#define NM (N_NODES * 256)

// parms arena offsets (u16 elements)
#define P_CONV_BIAS 0
#define P_POOL_W    768
#define P_POOL_ROOT 6912
#define P_POOL_BIAS 7680
#define P_FC1_W     7688
#define P_FC1_B     204296
#define P_W_IH      204552
#define P_B_IH      466696
#define P_B_HH      467720
#define P_FC2_W     468744
#define P_FC2_B     469256
#define P_TOTAL     469264

__device__ __forceinline__ float b2f(u16 u) {
    union { unsigned int i; float f; } v; v.i = ((unsigned int)u) << 16; return v.f;
}
__device__ __forceinline__ u16 f2b(float f) {
    union { float f; unsigned int i; } v; v.f = f;
    unsigned int x = v.i;
    return (u16)((x + 0x7fffu + ((x >> 16) & 1u)) >> 16);
}
__device__ __forceinline__ float wred(float s) {
    #pragma unroll
    for (int off = 32; off > 0; off >>= 1) s += __shfl_down(s, off);
    return s;
}
__device__ __forceinline__ float fdot2u(unsigned a, unsigned b, float c) {
#if __has_builtin(__builtin_amdgcn_fdot2)
    union { unsigned u; h2v h; } ua, ub; ua.u = a; ub.u = b;
    return __builtin_amdgcn_fdot2(ua.h, ub.h, c, false);
#else
    union { unsigned u; g2v h; } ua, ub; ua.u = a; ub.u = b;
    return c + (float)ua.h[0] * (float)ub.h[0] + (float)ua.h[1] * (float)ub.h[1];
#endif
}
__device__ __forceinline__ unsigned packh2(float a, float b) {
    g2v h = __builtin_amdgcn_cvt_pkrtz(a, b);
    union { g2v h; unsigned u; } v; v.h = h; return v.u;
}

// ---------------- init: zero flag + cnt + ctr ----------------
__global__ void k_init(unsigned int* __restrict__ flag, unsigned int* __restrict__ cnt,
                       unsigned int* __restrict__ ctr) {
    int i = blockIdx.x * 256 + threadIdx.x;
    if (i < 64) flag[i] = 0u;
    if (i < NSEG) { cnt[i] = 0u; ctr[i] = 0u; }
}

// ---------------- dtype detection (parallel) ----------------
__global__ void k_detect1(const u16* __restrict__ xr, int n, unsigned int* __restrict__ fb) {
    unsigned int local = 0;
    for (int i = blockIdx.x * 256 + threadIdx.x; i < n; i += 64 * 256) {
        unsigned int u = xr[i];
        if (((u >> 7) & 0xFFu) == 0xFFu) local++;
    }
    local = (unsigned int)wred((float)local);
    if ((threadIdx.x & 63) == 0 && local) atomicAdd(&fb[1], local);
}
__global__ void k_detect2(unsigned int* __restrict__ fb) {
    fb[0] = (fb[1] > 8u) ? 1u : 0u;
}

__device__ __forceinline__ u16 load_cvt(const void* src, size_t i, bool f32) {
    return f32 ? f2b(((const float*)src)[i]) : ((const u16*)src)[i];
}

// ---------------- one-shot param canonicalization ----------------
__global__ void k_cvt_all(const void* conv_bias, const void* pool_W, const void* pool_root,
                          const void* pool_bias, const void* fc1_W, const void* fc1_b,
                          const void* W_ih, const void* b_ih, const void* b_hh,
                          const void* fc2_W, const void* fc2_b,
                          u16* __restrict__ parms, const unsigned int* __restrict__ flag) {
    int i = blockIdx.x * 256 + threadIdx.x;
    if (i >= P_TOTAL) return;
    bool f32 = (*flag != 0u);
    u16 v;
    if      (i < P_CONV_BIAS + 768)    v = load_cvt(conv_bias, i - P_CONV_BIAS, f32);
    else if (i < P_POOL_W + 6144)      v = load_cvt(pool_W,    i - P_POOL_W, f32);
    else if (i < P_POOL_ROOT + 768)    v = load_cvt(pool_root, i - P_POOL_ROOT, f32);
    else if (i < P_POOL_BIAS + 1)      v = load_cvt(pool_bias, i - P_POOL_BIAS, f32);
    else if (i < P_FC1_W && i >= P_POOL_BIAS) return;        // alignment gap
    else if (i < P_FC1_W + 196608)     v = load_cvt(fc1_W,    i - P_FC1_W, f32);
    else if (i < P_FC1_B + 256)        v = load_cvt(fc1_b,    i - P_FC1_B, f32);
    else if (i < P_W_IH + 262144)      v = load_cvt(W_ih,     i - P_W_IH, f32);
    else if (i < P_B_IH + 1024)        v = load_cvt(b_ih,     i - P_B_IH, f32);
    else if (i < P_B_HH + 1024)        v = load_cvt(b_hh,     i - P_B_HH, f32);
    else if (i < P_FC2_W + 512)        v = load_cvt(fc2_W,    i - P_FC2_W, f32);
    else if (i < P_FC2_B + 2)          v = load_cvt(fc2_b,    i - P_FC2_B, f32);
    else return;
    parms[i] = v;
}

// stage x (canonical bf16) into xc[:, 512:768]; layer 2 overwrites only after layer 0+1 consumed
__global__ void k_stage_x(const void* __restrict__ src, u16* __restrict__ xc,
                          const unsigned int* __restrict__ flag) {
    int i = blockIdx.x * 256 + threadIdx.x;
    if (i >= N_NODES * 256) return;
    u16 v = load_cvt(src, i, *flag != 0u);
    int n = i >> 8, f = i & 255;
    xc[(size_t)n * 768 + 512 + f] = v;
}

// ---------------- degree counts ----------------
__global__ void k_count(const int* __restrict__ dst, const int* __restrict__ et,
                        unsigned int* __restrict__ cnt) {
    int e = blockIdx.x * 256 + threadIdx.x;
    if (e < N_EDGES) {
        unsigned d = (unsigned)dst[e]; if (d >= N_NODES) d = 0;
        unsigned r = (unsigned)et[e] & 7u;
        atomicAdd(&cnt[d * 8 + r], 1u);
    }
}
__global__ void k_inv(const unsigned int* __restrict__ cnt, float* __restrict__ inv, int n) {
    int i = blockIdx.x * 256 + threadIdx.x;
    if (i < n) {
        unsigned int c = cnt[i];
        inv[i] = 1.0f / (float)(c < 1u ? 1u : c);
    }
}

// ---------------- prefix scan (exclusive) over cnt[160000] ----------------
__global__ void k_scan1(const unsigned int* __restrict__ cnt, unsigned int* __restrict__ seg,
                        unsigned int* __restrict__ bsum) {
    __shared__ unsigned int s[256];
    int t = threadIdx.x, i = blockIdx.x * 256 + t;
    unsigned int v = (i < NSEG) ? cnt[i] : 0u;
    s[t] = v;
    __syncthreads();
    for (int off = 1; off < 256; off <<= 1) {
        unsigned int add = (t >= off) ? s[t - off] : 0u;
        __syncthreads();
        s[t] += add;
        __syncthreads();
    }
    if (i < NSEG) seg[i] = s[t] - v;
    if (t == 255) bsum[blockIdx.x] = s[255];
}
__global__ void k_scan2(unsigned int* __restrict__ bsum, int nb) {
    __shared__ unsigned int s[1024];
    int t = threadIdx.x;
    unsigned int v = (t < nb) ? bsum[t] : 0u;
    s[t] = v;
    __syncthreads();
    for (int off = 1; off < 1024; off <<= 1) {
        unsigned int add = (t >= off) ? s[t - off] : 0u;
        __syncthreads();
        s[t] += add;
        __syncthreads();
    }
    if (t < nb) bsum[t] = s[t] - v;
}
__global__ void k_scan3(unsigned int* __restrict__ seg, const unsigned int* __restrict__ bsum) {
    int i = blockIdx.x * 256 + threadIdx.x;
    if (i < NSEG) seg[i] += bsum[i >> 8];
    if (i == 0) seg[NSEG] = N_EDGES;
}
// place edges into (dst,rel)-sorted order; skey = src node id
__global__ void k_place(const int* __restrict__ src, const int* __restrict__ dst,
                        const int* __restrict__ et, const unsigned int* __restrict__ seg,
                        unsigned int* __restrict__ ctr, const float* __restrict__ inv,
                        unsigned int* __restrict__ skey, float* __restrict__ sw) {
    int e = blockIdx.x * 256 + threadIdx.x;
    if (e >= N_EDGES) return;
    unsigned s = (unsigned)src[e]; if (s >= N_NODES) s = 0;
    unsigned d = (unsigned)dst[e]; if (d >= N_NODES) d = 0;
    unsigned r = (unsigned)et[e] & 7u;
    unsigned key = d * 8 + r;
    unsigned pos = seg[key] + atomicAdd(&ctr[key], 1u);
    skey[pos] = s;
    sw[pos] = inv[key];
}

// ---------------- weight prep: W~t [l][256 out][2304 in] (k<2048: rel, k>=2048: root) ---------
__global__ void k_transpose2(const void* __restrict__ conv_W, const void* __restrict__ conv_root,
                             u16* __restrict__ Wt, const unsigned int* __restrict__ flag) {
    int idx = blockIdx.x * 256 + threadIdx.x;
    if (idx >= 3 * 256 * 2304) return;
    bool f32 = (*flag != 0u);
    int k = idx % 2304;
    int o = (idx / 2304) % 256;
    int l = idx / (2304 * 256);
    u16 v;
    if (k < 2048) {
        int r = k >> 8, i = k & 255;
        v = load_cvt(conv_W, ((size_t)((l * 8 + r) * 256 + i)) * 256 + o, f32);
    } else {
        int i = k - 2048;
        v = load_cvt(conv_root, ((size_t)(l * 256 + i)) * 256 + o, f32);
    }
    Wt[idx] = v;
}
// W_hh [j][i] -> packed f16 pairs whh2[i2][j]
__global__ void k_whh2(const void* __restrict__ W_hh, unsigned int* __restrict__ whh2,
                       const unsigned int* __restrict__ flag) {
    int idx = blockIdx.x * 256 + threadIdx.x;     // 128*1024
    if (idx >= 128 * 1024) return;
    int i2 = idx >> 10, j = idx & 1023;
    bool f32 = (*flag != 0u);
    float a, b;
    if (f32) {
        a = ((const float*)W_hh)[j * 256 + 2 * i2];
        b = ((const float*)W_hh)[j * 256 + 2 * i2 + 1];
    } else {
        a = b2f(((const u16*)W_hh)[j * 256 + 2 * i2]);
        b = b2f(((const u16*)W_hh)[j * 256 + 2 * i2 + 1]);
    }
    whh2[idx] = packh2(a, b);
}

// ---------------- gather inputs: Y[d][rr*256+f] = sum_e sw * x[s][f], RC rels from r0 --------
__launch_bounds__(256)
__global__ void k_gather_y(const unsigned int* __restrict__ seg,
                           const unsigned int* __restrict__ skey,
                           const float* __restrict__ sw,
                           const u16* __restrict__ xprev,   // stride 768
                           u16* __restrict__ Y, int r0, int RC) {
    int d = blockIdx.x, f = threadIdx.x;
    for (int rr = 0; rr < RC; ++rr) {
        int r = r0 + rr;
        unsigned nb = seg[d * 8 + r], ne = seg[d * 8 + r + 1];
        float acc = 0.0f;
        for (unsigned i = nb; i < ne; ++i)
            acc += sw[i] * b2f(xprev[(size_t)skey[i] * 768 + f]);
        Y[((size_t)d * RC + rr) * 256 + f] = f2b(acc);
    }
}

// ---------------- fused GEMM: [20000, KY(+256 root)] x W~t -> out ----------------
// grid (2, 313): blockIdx.x = N-half (128 cols), blockIdx.y = 64-row M tile.
// EPI: 0 = bias+relu -> xc (coalesced via LDS transpose); 1 = agg = val+bias;
//      2 = agg += val; 3 = relu(agg+val) -> xc.   INCR: include root piece (k=2048..2303).
template<int EPI, int INCR>
__launch_bounds__(256)
__global__ void k_gemm2(const u16* __restrict__ Y, int strideY, int KY,
                        const u16* __restrict__ xroot, const u16* __restrict__ Bt,
                        int kbase, const u16* __restrict__ bias,
                        float* __restrict__ agg, u16* __restrict__ xc, int colbase) {
    __shared__ u16 lb[128 * 72];                  // B chunk [128 n][64 k], stride 72 (pad)
    int n0 = blockIdx.x * 128;
    int wave = threadIdx.x >> 6, lane = threadIdx.x & 63;
    int m0 = blockIdx.y * 64 + wave * 16;
    int mrow = lane & 15, quad = lane >> 4;
    int mclamp = m0 + mrow; if (mclamp > N_NODES - 1) mclamp = N_NODES - 1;

    f4 acc[8];
    #pragma unroll
    for (int nt = 0; nt < 8; ++nt) acc[nt] = (f4){0.0f, 0.0f, 0.0f, 0.0f};

    int cy = KY >> 6;
    int nchunks = cy + (INCR ? 4 : 0);
    int brow = threadIdx.x >> 1;
    int bcol = (threadIdx.x & 1) * 32;
    const u16* bsrc = Bt + (size_t)(n0 + brow) * 2304 + bcol;
    u16* bdst = lb + brow * 72 + bcol;

    for (int ck = 0; ck < nchunks; ++ck) {
        bool isroot = INCR && (ck >= cy);
        int kg = isroot ? (2048 + ((ck - cy) << 6)) : (kbase + (ck << 6));
        __syncthreads();
        #pragma unroll
        for (int c = 0; c < 4; ++c)
            *(bf8*)(bdst + c * 8) = *(const bf8*)(bsrc + kg + c * 8);
        __syncthreads();
        const u16* arow = isroot ? (xroot + (size_t)mclamp * 768 + ((ck - cy) << 6))
                                 : (Y + (size_t)mclamp * strideY + (ck << 6));
        bf8 a0 = *(const bf8*)(arow + quad * 8);
        bf8 a1 = *(const bf8*)(arow + quad * 8 + 32);
        #pragma unroll
        for (int nt = 0; nt < 8; ++nt) {
            const u16* lbp = lb + (nt * 16 + mrow) * 72 + quad * 8;
            bf8 b0 = *(const bf8*)(lbp);
            bf8 b1 = *(const bf8*)(lbp + 32);
            acc[nt] = __builtin_amdgcn_mfma_f32_16x16x32_bf16(a0, b0, acc[nt], 0, 0, 0);
            acc[nt] = __builtin_amdgcn_mfma_f32_16x16x32_bf16(a1, b1, acc[nt], 0, 0, 0);
        }
    }

    if (EPI == 0) {
        __syncthreads();
        u16* tb = lb + wave * 2176;               // 16 rows x stride 136
        #pragma unroll
        for (int nt = 0; nt < 8; ++nt)
            #pragma unroll
            for (int v = 0; v < 4; ++v) {
                int o = n0 + nt * 16 + mrow;
                float val = acc[nt][v] + b2f(bias[o]);
                val = val > 0.0f ? val : 0.0f;
                tb[(quad * 4 + v) * 136 + nt * 16 + mrow] = f2b(val);
            }
        __syncthreads();
        int srow = lane >> 2, scol = (lane & 3) * 32;
        int m = m0 + srow;
        if (m < N_NODES) {
            u16* dst = xc + (size_t)m * 768 + colbase + n0 + scol;
            const u16* srcp = tb + srow * 136 + scol;
            #pragma unroll
            for (int c = 0; c < 4; ++c)
                *(bf8*)(dst + c * 8) = *(const bf8*)(srcp + c * 8);
        }
    } else {
        #pragma unroll
        for (int nt = 0; nt < 8; ++nt)
            #pragma unroll
            for (int v = 0; v < 4; ++v) {
                int m = m0 + quad * 4 + v;
                if (m >= N_NODES) continue;
                int o = n0 + nt * 16 + mrow;
                if (EPI == 1) {
                    agg[(size_t)m * 256 + o] = acc[nt][v] + b2f(bias[o]);
                } else if (EPI == 2) {
                    agg[(size_t)m * 256 + o] += acc[nt][v];
                } else {
                    float s = agg[(size_t)m * 256 + o] + acc[nt][v];
                    s = s > 0.0f ? s : 0.0f;
                    xc[(size_t)m * 768 + colbase + o] = f2b(s);
                }
            }
    }
}

// ---------------- pool scorer: one wave per node, all 9 dots fused ----------------
__launch_bounds__(256)
__global__ void k_pool(const u16* __restrict__ xc, const u16* __restrict__ parms,
                       float* __restrict__ p, float* __restrict__ score) {
    int n = blockIdx.x * 4 + (threadIdx.x >> 6);
    if (n >= N_NODES) return;
    int lane = threadIdx.x & 63;
    const u16* xr = xc + (size_t)n * 768;
    float acc[9];
    #pragma unroll
    for (int rr = 0; rr < 9; ++rr) acc[rr] = 0.0f;
    #pragma unroll
    for (int q = 0; q < 12; ++q) {
        int f = lane + 64 * q;
        float xv = b2f(xr[f]);
        #pragma unroll
        for (int rr = 0; rr < 8; ++rr)
            acc[rr] += xv * b2f(parms[P_POOL_W + rr * 768 + f]);
        acc[8] += xv * b2f(parms[P_POOL_ROOT + f]);
    }
    #pragma unroll
    for (int rr = 0; rr < 9; ++rr) acc[rr] = wred(acc[rr]);
    if (lane == 0) {
        #pragma unroll
        for (int rr = 0; rr < 8; ++rr) p[rr * N_NODES + n] = acc[rr];
        score[n] = acc[8] + b2f(parms[P_POOL_BIAS]);
    }
}
__global__ void k_scatter_pool(const int* __restrict__ src, const int* __restrict__ dst,
                               const int* __restrict__ et, const float* __restrict__ inv,
                               const float* __restrict__ p, float* __restrict__ score) {
    int e = blockIdx.x * 256 + threadIdx.x;
    if (e >= N_EDGES) return;
    int r = et[e] & 7;
    unsigned s = (unsigned)src[e]; if (s >= N_NODES) s = 0;
    unsigned d = (unsigned)dst[e]; if (d >= N_NODES) d = 0;
    atomicAdd(&score[d], inv[d * 8 + r] * p[r * N_NODES + s]);
}

// ---------------- per-graph top-K sort ----------------
__launch_bounds__(256)
__global__ void k_sort(const float* __restrict__ score, unsigned int* __restrict__ topidx,
                       float* __restrict__ topv) {
    __shared__ unsigned long long keys[512];
    __shared__ float vals[512];
    int g = blockIdx.x, tid = threadIdx.x;
    for (int i = tid; i < 512; i += 256) {
        unsigned long long key;
        float v = 0.0f;
        if (i < NPG) {
            v = tanhf(score[g * NPG + i]);
            unsigned int u = __float_as_uint(v);
            u = (u & 0x80000000u) ? ~u : (u | 0x80000000u);
            u = ~u;
            key = ((unsigned long long)u << 32) | (unsigned int)i;
        } else {
            key = 0xFFFFFFFFFFFFFFFFull;
        }
        keys[i] = key;
        vals[i] = v;
    }
    __syncthreads();
    for (int k = 2; k <= 512; k <<= 1)
        for (int j = k >> 1; j > 0; j >>= 1) {
            for (int i = tid; i < 512; i += 256) {
                int ixj = i ^ j;
                if (ixj > i) {
                    bool up = ((i & k) == 0);
                    unsigned long long a = keys[i], b = keys[ixj];
                    if ((a > b) == up) { keys[i] = b; keys[ixj] = a; }
                }
            }
            __syncthreads();
        }
    if (tid < KTOP) {
        int idx = (int)(keys[tid] & 511u);
        topidx[g * 256 + tid] = (unsigned)idx;
        topv[g * 256 + tid] = vals[idx];
    }
}

// ---------------- parallel weighted readout ----------------
__launch_bounds__(256)
__global__ void k_readout(const unsigned int* __restrict__ topidx,
                          const float* __restrict__ topv,
                          const u16* __restrict__ xc, float* __restrict__ readout) {
    __shared__ unsigned int sidx[KTOP];
    __shared__ float sv[KTOP];
    __shared__ float part[256];
    int g = blockIdx.x, cb = blockIdx.y;
    int tid = threadIdx.x;
    if (tid < KTOP) { sidx[tid] = topidx[g * 256 + tid]; sv[tid] = topv[g * 256 + tid]; }
    __syncthreads();
    int fl = tid & 63, ng = tid >> 6;
    int f = cb * 64 + fl;
    float acc = 0.0f;
    for (int j = ng; j < KTOP; j += 4)
        acc += sv[j] * b2f(xc[(size_t)(g * NPG + sidx[j]) * 768 + f]);
    part[tid] = acc;
    __syncthreads();
    if (tid < 64) {
        float s = part[tid] + part[64 + tid] + part[128 + tid] + part[192 + tid];
        readout[(size_t)g * 768 + cb * 64 + tid] = s * (1.0f / (float)KTOP);
    }
}

// ---------------- fc1 + LSTM input precompute ----------------
__global__ void k_fc1(const float* __restrict__ readout, const u16* __restrict__ parms,
                      float* __restrict__ h1) {
    int wid = blockIdx.x * 4 + (threadIdx.x >> 6);
    if (wid >= NGRAPH * 256) return;
    int g = wid >> 8, o = wid & 255, lane = threadIdx.x & 63;
    const float* rr = readout + (size_t)g * 768;
    const u16* w = parms + P_FC1_W + (size_t)o * 768;
    float s = 0.0f;
    #pragma unroll
    for (int q = 0; q < 12; ++q) { int f = lane + 64 * q; s += rr[f] * b2f(w[f]); }
    s = wred(s);
    if (lane == 0) { s += b2f(parms[P_FC1_B + o]); h1[g * 256 + o] = s > 0.0f ? s : 0.0f; }
}
__global__ void k_gx(const float* __restrict__ h1, const u16* __restrict__ parms,
                     float* __restrict__ gx) {
    int wid = blockIdx.x * 4 + (threadIdx.x >> 6);
    if (wid >= NGRAPH * 1024) return;
    int t = wid >> 10, j = wid & 1023, lane = threadIdx.x & 63;
    const float* xr = h1 + t * 256;
    const u16* w = parms + P_W_IH + (size_t)j * 256;
    float s = 0.0f;
    #pragma unroll
    for (int q = 0; q < 4; ++q) { int f = lane + 64 * q; s += xr[f] * b2f(w[f]); }
    s = wred(s);
    if (lane == 0) gx[t * 1024 + j] = s + b2f(parms[P_B_IH + j]) + b2f(parms[P_B_HH + j]);
}

// ---------------- sequential LSTM: f16-dot2, half of W_hh register-resident ----------------
__launch_bounds__(1024, 4)
__global__ void k_lstm(const float* __restrict__ gx, const unsigned int* __restrict__ whh2,
                       const u16* __restrict__ parms, void* __restrict__ out,
                       const unsigned int* __restrict__ flag) {
    __shared__ float hs[256];
    __shared__ unsigned int hs2[128];
    __shared__ float gs[1024];
    __shared__ float red[2];
    int tid = threadIdx.x;
    unsigned int wreg[64];
    #pragma unroll
    for (int i = 0; i < 64; ++i) wreg[i] = whh2[i * 1024 + tid];
    if (tid < 256) hs[tid] = 0.0f;
    if (tid < 128) hs2[tid] = 0u;
    float c = 0.0f;
    __syncthreads();
    for (int t = 0; t < NGRAPH; ++t) {
        float g = gx[t * 1024 + tid];
        #pragma unroll
        for (int i = 0; i < 64; ++i) g = fdot2u(wreg[i], hs2[i], g);
        #pragma unroll 8
        for (int i = 64; i < 128; ++i) g = fdot2u(whh2[i * 1024 + tid], hs2[i], g);
        gs[tid] = g;
        __syncthreads();
        if (tid < 256) {
            float gi = 1.0f / (1.0f + expf(-gs[tid]));
            float gf = 1.0f / (1.0f + expf(-gs[256 + tid]));
            float gg = tanhf(gs[512 + tid]);
            float go = 1.0f / (1.0f + expf(-gs[768 + tid]));
            c = gf * c + gi * gg;
            float h = go * tanhf(c);
            hs[tid] = h;
            float ho = __shfl(h, (tid & 63) ^ 1);
            if (!(tid & 1)) hs2[tid >> 1] = packh2(h, ho);
        }
        __syncthreads();
    }
    if (tid < 128) {
        int cls = tid >> 6, lane = tid & 63;
        float s = 0.0f;
        #pragma unroll
        for (int q = 0; q < 4; ++q) {
            int d = lane + 64 * q;
            s += hs[d] * b2f(parms[P_FC2_W + cls * 256 + d]);
        }
        s = wred(s);
        if (lane == 0) red[cls] = s + b2f(parms[P_FC2_B + cls]);
    }
    __syncthreads();
    if (tid == 0) {
        float l0 = red[0], l1 = red[1];
        float m = fmaxf(l0, l1);
        float lse = m + logf(expf(l0 - m) + expf(l1 - m));
        float o0 = l0 - lse, o1 = l1 - lse;
        if (*flag) { ((float*)out)[0] = o0; ((float*)out)[1] = o1; }
        else       { ((u16*)out)[0] = f2b(o0); ((u16*)out)[1] = f2b(o1); }
    }
}

// ---------------- workspace plan ----------------
struct WS {
    unsigned int* flag; unsigned int* cnt; float* inv; unsigned int* seg; unsigned int* ctr;
    unsigned int* skey; float* sw; unsigned int* bsum;
    u16* Wt2; u16* Y; float* agg; u16* xc; float* p; float* score;
    unsigned int* topidx; float* topv;
    float* readout; float* h1; float* gx; unsigned int* whh2; u16* parms;
    size_t need;
};
static WS plan(char* base, int RC) {
    WS w; size_t off = 0;
    auto take = [&](size_t bytes) -> char* {
        char* p = base + off; off += (bytes + 255) & ~(size_t)255; return p;
    };
    w.flag    = (unsigned int*)take(256);
    w.cnt     = (unsigned int*)take((size_t)NSEG * 4);
    w.inv     = (float*)take((size_t)NSEG * 4);
    w.seg     = (unsigned int*)take((size_t)(NSEG + 1) * 4);
    w.ctr     = (unsigned int*)take((size_t)NSEG * 4);
    w.skey    = (unsigned int*)take((size_t)N_EDGES * 4);
    w.sw      = (float*)take((size_t)N_EDGES * 4);
    w.bsum    = (unsigned int*)take(1024 * 4);
    w.Wt2     = (u16*)take((size_t)3 * 256 * 2304 * 2);
    w.Y       = (u16*)take((size_t)N_NODES * RC * 256 * 2);
    w.agg     = (RC < 8) ? (float*)take((size_t)NM * 4) : nullptr;
    w.xc      = (u16*)take((size_t)N_NODES * 768 * 2);
    w.p       = (float*)take((size_t)8 * N_NODES * 4);
    w.score   = (float*)take((size_t)N_NODES * 4);
    w.topidx  = (unsigned int*)take((size_t)NGRAPH * 256 * 4);
    w.topv    = (float*)take((size_t)NGRAPH * 256 * 4);
    w.readout = (float*)take((size_t)NGRAPH * 768 * 4);
    w.h1      = (float*)take((size_t)NGRAPH * 256 * 4);
    w.gx      = (float*)take((size_t)NGRAPH * 1024 * 4);
    w.whh2    = (unsigned int*)take((size_t)128 * 1024 * 4);
    w.parms   = (u16*)take((size_t)P_TOTAL * 2);
    w.need = off;
    return w;
}

static void run_layers2(const WS& w, int RC, hipStream_t stream) {
    const dim3 ggrid(2, 313);
    const int npass = 8 / RC;
    const int KY = RC * 256;
    for (int l = 0; l < 3; ++l) {
        const u16* xprev = w.xc + (l == 0 ? 512 : (l - 1) * 256);
        const u16* Bt = w.Wt2 + (size_t)l * 2304 * 256;
        const u16* bias = w.parms + P_CONV_BIAS + l * 256;
        for (int p = 0; p < npass; ++p) {
            k_gather_y<<<N_NODES, 256, 0, stream>>>(w.seg, w.skey, w.sw, xprev,
                                                    w.Y, p * RC, RC);
            int kbase = p * RC * 256;
            if (npass == 1)
                k_gemm2<0, 1><<<ggrid, 256, 0, stream>>>(w.Y, KY, KY, xprev, Bt, kbase,
                                                         bias, w.agg, w.xc, l * 256);
            else if (p == 0)
                k_gemm2<1, 1><<<ggrid, 256, 0, stream>>>(w.Y, KY, KY, xprev, Bt, kbase,
                                                         bias, w.agg, w.xc, l * 256);
            else if (p == npass - 1)
                k_gemm2<3, 0><<<ggrid, 256, 0, stream>>>(w.Y, KY, KY, xprev, Bt, kbase,
                                                         bias, w.agg, w.xc, l * 256);
            else
                k_gemm2<2, 0><<<ggrid, 256, 0, stream>>>(w.Y, KY, KY, xprev, Bt, kbase,
                                                         bias, w.agg, w.xc, l * 256);
        }
    }
}

extern "C" void kernel_launch(void* const* d_in, const int* in_sizes, int n_in,
                              void* d_out, int out_size, void* d_ws, size_t ws_size,
                              hipStream_t stream) {
    (void)in_sizes; (void)n_in; (void)out_size;
    const void* x        = d_in[0];
    const int* edge_index= (const int*)d_in[1];
    const int* edge_attr = (const int*)d_in[2];
    const void* conv_W   = d_in[4];
    const void* conv_root= d_in[5];
    const void* conv_bias= d_in[6];
    const void* pool_W   = d_in[7];
    const void* pool_root= d_in[8];
    const void* pool_bias= d_in[9];
    const void* fc1_W    = d_in[10];
    const void* fc1_b    = d_in[11];
    const void* W_ih     = d_in[12];
    const void* W_hh     = d_in[13];
    const void* b_ih     = d_in[14];
    const void* b_hh     = d_in[15];
    const void* fc2_W    = d_in[16];
    const void* fc2_b    = d_in[17];

    const int* e_src = edge_index;
    const int* e_dst = edge_index + N_EDGES;

    int RC = 1;
    if (plan((char*)d_ws, 8).need <= ws_size)      RC = 8;
    else if (plan((char*)d_ws, 4).need <= ws_size) RC = 4;
    else if (plan((char*)d_ws, 2).need <= ws_size) RC = 2;
    WS w = plan((char*)d_ws, RC);

    k_init<<<(NSEG + 255) / 256, 256, 0, stream>>>(w.flag, w.cnt, w.ctr);
    k_detect1<<<64, 256, 0, stream>>>((const u16*)x, 1 << 20, w.flag);
    k_detect2<<<1, 1, 0, stream>>>(w.flag);

    k_count<<<1250, 256, 0, stream>>>(e_dst, edge_attr, w.cnt);
    k_inv<<<(NSEG + 255) / 256, 256, 0, stream>>>(w.cnt, w.inv, NSEG);
    k_scan1<<<625, 256, 0, stream>>>(w.cnt, w.seg, w.bsum);
    k_scan2<<<1, 1024, 0, stream>>>(w.bsum, 625);
    k_scan3<<<(NSEG + 255) / 256, 256, 0, stream>>>(w.seg, w.bsum);
    k_place<<<1250, 256, 0, stream>>>(e_src, e_dst, edge_attr, w.seg, w.ctr, w.inv,
                                      w.skey, w.sw);

    k_cvt_all<<<(P_TOTAL + 255) / 256, 256, 0, stream>>>(
        conv_bias, pool_W, pool_root, pool_bias, fc1_W, fc1_b,
        W_ih, b_ih, b_hh, fc2_W, fc2_b, w.parms, w.flag);

    k_stage_x<<<20000, 256, 0, stream>>>(x, w.xc, w.flag);
    k_transpose2<<<6912, 256, 0, stream>>>(conv_W, conv_root, w.Wt2, w.flag);
    k_whh2<<<512, 256, 0, stream>>>(W_hh, w.whh2, w.flag);

    run_layers2(w, RC, stream);

    k_pool<<<5000, 256, 0, stream>>>(w.xc, w.parms, w.p, w.score);
    k_scatter_pool<<<1250, 256, 0, stream>>>(e_src, e_dst, edge_attr, w.inv, w.p, w.score);
    k_sort<<<NGRAPH, 256, 0, stream>>>(w.score, w.topidx, w.topv);
    k_readout<<<dim3(NGRAPH, 12), 256, 0, stream>>>(w.topidx, w.topv, w.xc, w.readout);
    k_fc1<<<2560, 256, 0, stream>>>(w.readout, w.parms, w.h1);
    k_gx<<<10240, 256, 0, stream>>>(w.h1, w.parms, w.gx);
    k_lstm<<<1, 1024, 0, stream>>>(w.gx, w.whh2, w.parms, d_out, w.flag);
}